// Round 2
// baseline (316.143 us; speedup 1.0000x reference)
//
#include <hip/hip_runtime.h>
#include <hip/hip_bf16.h>
#include <math.h>

// Problem constants: B=8, S=1000, E=1024, H=16, D=64
constexpr int B_ = 8, S_ = 1000, E_ = 1024, H_ = 16, D_ = 64;
constexpr int M_ = B_ * S_;   // 8000 rows

using bf16x8 = __attribute__((ext_vector_type(8))) __bf16;
using u16x8  = __attribute__((ext_vector_type(8))) unsigned short;
using f32x4  = __attribute__((ext_vector_type(4))) float;

static __device__ __forceinline__ unsigned short f2bf(float f) {
    union { float f; unsigned u; } c; c.f = f;
    return (unsigned short)((c.u + 0x7FFF + ((c.u >> 16) & 1)) >> 16);
}
static __device__ __forceinline__ unsigned short f2bf_fast(float f) {
    union { float f; unsigned u; } c; c.f = f;
    return (unsigned short)((c.u + 0x8000) >> 16);   // round-half-up
}
static __device__ __forceinline__ float bfr2f(unsigned short s) {
    union { unsigned u; float f; } c; c.u = ((unsigned)s) << 16;
    return c.f;
}

// Async global->LDS DMA, 16B per lane. LDS dest is wave-uniform base;
// HW writes base + lane*16 (linear). Global source is per-lane.
static __device__ __forceinline__ void gld16(const unsigned short* g, unsigned short* lds) {
    __builtin_amdgcn_global_load_lds(
        (__attribute__((address_space(1))) void*)(g),
        (__attribute__((address_space(3))) void*)(lds), 16, 0, 0);
}

// ---------------------------------------------------------------------------
// Cast x (fp32 [M,E]) -> bf16.
// ---------------------------------------------------------------------------
__global__ __launch_bounds__(256) void cast_x_kernel(
    const float* __restrict__ x, unsigned short* __restrict__ xbf)
{
    const size_t i = ((size_t)blockIdx.x * 256 + threadIdx.x) * 4;
    float4 v = *(const float4*)(x + i);
    ushort4 o;
    o.x = f2bf(v.x); o.y = f2bf(v.y); o.z = f2bf(v.z); o.w = f2bf(v.w);
    *(ushort4*)(xbf + i) = o;
}

// ---------------------------------------------------------------------------
// Transpose+cast qkv weights: w[h][e][d] fp32 -> WT[(z*16+h)*64 + d][e] bf16.
// ---------------------------------------------------------------------------
__global__ __launch_bounds__(256) void transpose_wqkv_kernel(
    const float* __restrict__ wq, const float* __restrict__ wk,
    const float* __restrict__ wv, unsigned short* __restrict__ WT)
{
    __shared__ unsigned short Ts[64 * 65];
    const int et = blockIdx.x, zh = blockIdx.y;
    const int z = zh >> 4, h = zh & 15;
    const float* src = (z == 0 ? wq : z == 1 ? wk : wv) + (size_t)h * E_ * D_;

    const int d = threadIdx.x & 63;
    const int e0 = threadIdx.x >> 6;   // 0..3
    #pragma unroll
    for (int p = 0; p < 16; ++p) {
        const int e = e0 + p * 4;
        Ts[d * 65 + e] = f2bf(src[(size_t)(et * 64 + e) * D_ + d]);
    }
    __syncthreads();
    const int e = threadIdx.x & 63;
    const int d0 = threadIdx.x >> 6;
    #pragma unroll
    for (int p = 0; p < 16; ++p) {
        const int dd = d0 + p * 4;
        WT[((size_t)zh * 64 + dd) * E_ + et * 64 + e] = Ts[dd * 65 + e];
    }
}

// ---------------------------------------------------------------------------
// Transpose+cast wp: wp[e][f] fp32 -> wpT[f][e] bf16. grid (16 e, 16 f).
// ---------------------------------------------------------------------------
__global__ __launch_bounds__(256) void transpose_wp_kernel(
    const float* __restrict__ wp, unsigned short* __restrict__ wpT)
{
    __shared__ unsigned short Ts[64 * 65];
    const int et = blockIdx.x, ft = blockIdx.y;
    const int f = threadIdx.x & 63;
    const int e0 = threadIdx.x >> 6;
    #pragma unroll
    for (int p = 0; p < 16; ++p) {
        const int e = e0 + p * 4;
        Ts[f * 65 + e] = f2bf(wp[(size_t)(et * 64 + e) * E_ + ft * 64 + f]);
    }
    __syncthreads();
    const int e = threadIdx.x & 63;
    const int f0 = threadIdx.x >> 6;
    #pragma unroll
    for (int p = 0; p < 16; ++p) {
        const int ff = f0 + p * 4;
        wpT[((size_t)(ft * 64 + ff)) * E_ + et * 64 + e] = Ts[ff * 65 + e];
    }
}

// ---------------------------------------------------------------------------
// Transpose v: vb[bh][s][d] bf16 -> vt[bh][d][s] bf16. grid (16 s-tiles, 128 bh).
// ---------------------------------------------------------------------------
__global__ __launch_bounds__(256) void transpose_v_kernel(
    const unsigned short* __restrict__ vb, unsigned short* __restrict__ vt)
{
    __shared__ unsigned short Ts[64 * 65];
    const int st = blockIdx.x, bh = blockIdx.y;
    const size_t ibase = (size_t)bh * S_ * D_;
    const size_t obase = (size_t)bh * D_ * S_;

    const int d = threadIdx.x & 63;
    const int s0 = threadIdx.x >> 6;   // 0..3
    #pragma unroll
    for (int p = 0; p < 16; ++p) {
        const int s = s0 + p * 4;
        const int srow = st * 64 + s;
        Ts[s * 65 + d] = (srow < S_) ? vb[ibase + (size_t)srow * D_ + d] : 0;
    }
    __syncthreads();
    const int s = threadIdx.x & 63;
    const int d0 = threadIdx.x >> 6;
    const int scol = st * 64 + s;
    if (scol < S_) {
        #pragma unroll
        for (int p = 0; p < 16; ++p) {
            const int dd = d0 + p * 4;
            vt[obase + (size_t)dd * S_ + scol] = Ts[s * 65 + dd];
        }
    }
}

// ---------------------------------------------------------------------------
// qkv projection: ONE dense GEMM [M=8000,K=1024] x [K,N=3072].
// R11: 2-phase double-buffered pipeline (T3 minimum recipe) + T1 chunked XCD
// swizzle. Stage tile t+1 into buf^1 BEFORE computing tile t from buf; single
// __syncthreads (drains vmcnt) at loop bottom -> loads in flight across the
// whole MFMA phase. Previous drain-before-compute structure measured 561 TF
// (89.7 us, MfmaUtil 22.6%). Do NOT pad LDS (global_load_lds is linear-dest).
// Bank conflicts (16-way on ds_read_b128) are expected; T2 swizzle is null at
// 2-phase (m230) -- only fix if/when moving to 8-phase.
// ---------------------------------------------------------------------------
__global__ __launch_bounds__(256) void qkv_mfma_kernel(
    const unsigned short* __restrict__ xbf, const unsigned short* __restrict__ WT,
    const float* __restrict__ bq, const float* __restrict__ bk,
    const float* __restrict__ bv,
    unsigned short* __restrict__ qb, unsigned short* __restrict__ kb,
    unsigned short* __restrict__ vb)
{
    __shared__ unsigned short As[2][128 * 64];   // 32 KB
    __shared__ unsigned short Bs[2][128 * 64];   // 32 KB

    const int tid  = threadIdx.x;
    const int wave = tid >> 6, lane = tid & 63;
    const int m16  = lane & 15, quad = lane >> 4;
    const int wm   = wave >> 1, wn = wave & 1;

    // T1 chunked XCD swizzle: 1512 blocks = 8 XCDs x 189. Dispatcher round-
    // robins flat id over XCDs, so f&7 == XCD. Each XCD owns ~7.9 contiguous
    // m-tiles -> A-panel reuse lands in that XCD's L2.
    const int f  = (int)(blockIdx.y * gridDim.x + blockIdx.x);
    const int fp = (f & 7) * 189 + (f >> 3);
    const int n0 = (fp % 24) * 128;
    const int m0 = (fp / 24) * 128;

    f32x4 acc[4][4];   // [nf][mf]
    #pragma unroll
    for (int nf = 0; nf < 4; ++nf)
        #pragma unroll
        for (int mf = 0; mf < 4; ++mf)
            acc[nf][mf] = (f32x4){0.f, 0.f, 0.f, 0.f};

    // DMA staging coords: issue i = wave*4+j covers LDS rows 8i..8i+7;
    // lane l supplies row 8i + (l>>3), cols ((l&7)*8 .. +7).
    const int lrow = lane >> 3;          // 0..7
    const int lcol = (lane & 7) << 3;    // 0,8,..,56

    int a_srow[4];
    int b_srow[4];
    #pragma unroll
    for (int j = 0; j < 4; ++j) {
        int r = m0 + (wave * 4 + j) * 8 + lrow;
        a_srow[j] = (r < M_) ? r : (M_ - 1);
        b_srow[j] = n0 + (wave * 4 + j) * 8 + lrow;
    }

    // prologue: stage tile 0 into buf 0, drain
    #pragma unroll
    for (int j = 0; j < 4; ++j) {
        const int i = wave * 4 + j;
        gld16(xbf + (size_t)a_srow[j] * E_ + lcol, &As[0][i * 512]);
        gld16(WT + (size_t)b_srow[j] * E_ + lcol, &Bs[0][i * 512]);
    }
    __syncthreads();

    int cur = 0;
    for (int kt = 0; kt < 16; ++kt) {
        // issue next-tile loads into the other buffer (in flight during MFMA)
        if (kt < 15) {
            const int kn = (kt + 1) * 64;
            #pragma unroll
            for (int j = 0; j < 4; ++j) {
                const int i = wave * 4 + j;
                gld16(xbf + (size_t)a_srow[j] * E_ + kn + lcol, &As[cur ^ 1][i * 512]);
                gld16(WT + (size_t)b_srow[j] * E_ + kn + lcol, &Bs[cur ^ 1][i * 512]);
            }
        }

        // compute tile kt from buf[cur] (lgkm waits only; vmcnt stays open)
        #pragma unroll
        for (int kh = 0; kh < 2; ++kh) {
            const int ko = kh * 32 + quad * 8;
            bf16x8 af[4];
            #pragma unroll
            for (int mf = 0; mf < 4; ++mf)
                af[mf] = *(const bf16x8*)&As[cur][(wm * 64 + mf * 16 + m16) * 64 + ko];
            #pragma unroll
            for (int nf = 0; nf < 4; ++nf) {
                const bf16x8 bfr = *(const bf16x8*)&Bs[cur][(wn * 64 + nf * 16 + m16) * 64 + ko];
                #pragma unroll
                for (int mf = 0; mf < 4; ++mf)
                    acc[nf][mf] = __builtin_amdgcn_mfma_f32_16x16x32_bf16(
                        af[mf], bfr, acc[nf][mf], 0, 0, 0);
            }
        }

        // single drain per tile: own loads landed + all waves' reads done
        __syncthreads();
        cur ^= 1;
    }

    // Epilogue: column n = n0 + wn*64 + nf*16 + m16 -> z = n>>10 (block-
    // uniform), h = (n>>6)&15 (wave-uniform), d = nf*16 + m16.
    const int z = n0 >> 10;
    const int h = ((n0 >> 6) + wn) & 15;
    unsigned short* const ob = (z == 0) ? qb : (z == 1) ? kb : vb;
    const float* const bz    = (z == 0) ? bq : (z == 1) ? bk : bv;

    float biasv[4];
    #pragma unroll
    for (int nf = 0; nf < 4; ++nf)
        biasv[nf] = bz[h * D_ + nf * 16 + m16];

    #pragma unroll
    for (int mf = 0; mf < 4; ++mf)
        #pragma unroll
        for (int r = 0; r < 4; ++r) {
            const int row = m0 + wm * 64 + mf * 16 + quad * 4 + r;
            if (row < M_) {
                const int b = row / S_, s = row % S_;
                const size_t obase = (((size_t)b * H_ + h) * S_ + s) * D_ + m16;
                #pragma unroll
                for (int nf = 0; nf < 4; ++nf)
                    ob[obase + nf * 16] = f2bf(acc[nf][mf][r] + biasv[nf]);
            }
        }
}

// ---------------------------------------------------------------------------
// Flash attention (unchanged from round 8).
// ---------------------------------------------------------------------------
__global__ __launch_bounds__(256) void attn_flash_kernel(
    const unsigned short* __restrict__ q, const unsigned short* __restrict__ k,
    const unsigned short* __restrict__ vt, unsigned short* __restrict__ ybf)
{
    constexpr int P_ = 72;
    __shared__ unsigned short Qs[64 * P_];
    __shared__ unsigned short Ks[64 * P_];
    __shared__ unsigned short Vt[64 * P_];   // [d][t]
    __shared__ unsigned short Ps[4][16 * P_];

    const int tid  = threadIdx.x;
    const int wave = tid >> 6, lane = tid & 63;
    const int m16  = lane & 15, quad = lane >> 4;
    const int qt = (int)gridDim.x - 1 - (int)blockIdx.x;   // long blocks first
    const int h = blockIdx.y, b = blockIdx.z;
    const size_t bh  = ((size_t)b * H_ + h) * S_;
    const size_t vtb = ((size_t)b * H_ + h) * (size_t)D_ * S_;
    const float sl2e = 0.031622776601683794f * 1.4426950408889634f;

    const int c8 = (tid & 7) * 8;
    const int r0 = tid >> 3;   // 0..31

    #pragma unroll
    for (int rr = 0; rr < 64; rr += 32) {
        const int r = r0 + rr;
        const int srow = qt * 64 + r;
        u16x8 val = {0, 0, 0, 0, 0, 0, 0, 0};
        if (srow < S_) val = *(const u16x8*)(q + (bh + srow) * D_ + c8);
        u16x8 o;
        #pragma unroll
        for (int j = 0; j < 8; ++j) o[j] = f2bf_fast(bfr2f(val[j]) * sl2e);
        *(u16x8*)&Qs[r * P_ + c8] = o;
    }
    __syncthreads();

    const bf16x8 qa0 = *(const bf16x8*)&Qs[(wave * 16 + m16) * P_ + quad * 8];
    const bf16x8 qa1 = *(const bf16x8*)&Qs[(wave * 16 + m16) * P_ + 32 + quad * 8];

    f32x4 O[4] = {{0,0,0,0},{0,0,0,0},{0,0,0,0},{0,0,0,0}};
    float l_i[4] = {0.f, 0.f, 0.f, 0.f};

    const int qrow_base = qt * 64 + wave * 16 + quad * 4;

    u16x8 kreg[2], vreg[2];
    #pragma unroll
    for (int i = 0; i < 2; ++i) {
        const int srow = r0 + i * 32;
        kreg[i] = *(const u16x8*)(k + (bh + srow) * D_ + c8);
        vreg[i] = *(const u16x8*)(vt + vtb + (size_t)(r0 + i * 32) * S_ + c8);
    }

    for (int tt = 0; tt <= qt; ++tt) {
        const int t0 = tt * 64;
        __syncthreads();
        #pragma unroll
        for (int i = 0; i < 2; ++i) {
            *(u16x8*)&Ks[(r0 + i * 32) * P_ + c8] = kreg[i];
            *(u16x8*)&Vt[(r0 + i * 32) * P_ + c8] = vreg[i];
        }
        __syncthreads();

        if (tt < qt) {
            const int nt0 = t0 + 64;
            #pragma unroll
            for (int i = 0; i < 2; ++i) {
                const int t = r0 + i * 32;
                const int srow = nt0 + t;
                u16x8 kv = {0,0,0,0,0,0,0,0}, vv = {0,0,0,0,0,0,0,0};
                if (srow < S_) kv = *(const u16x8*)(k + (bh + srow) * D_ + c8);
                if (nt0 + c8 < S_)
                    vv = *(const u16x8*)(vt + vtb + (size_t)t * S_ + nt0 + c8);
                kreg[i] = kv; vreg[i] = vv;
            }
        }

        f32x4 sc[4];
        #pragma unroll
        for (int ts = 0; ts < 4; ++ts) {
            const bf16x8 kb0 = *(const bf16x8*)&Ks[(ts * 16 + m16) * P_ + quad * 8];
            const bf16x8 kb1 = *(const bf16x8*)&Ks[(ts * 16 + m16) * P_ + 32 + quad * 8];
            f32x4 a = {0.f, 0.f, 0.f, 0.f};
            a = __builtin_amdgcn_mfma_f32_16x16x32_bf16(qa0, kb0, a, 0, 0, 0);
            a = __builtin_amdgcn_mfma_f32_16x16x32_bf16(qa1, kb1, a, 0, 0, 0);
            sc[ts] = a;
        }

        unsigned short* const pw = &Ps[wave][0];
        if (tt == qt) {
            #pragma unroll
            for (int ts = 0; ts < 4; ++ts) {
                const int t = t0 + ts * 16 + m16;
                #pragma unroll
                for (int r = 0; r < 4; ++r) {
                    float p = __builtin_amdgcn_exp2f(sc[ts][r]);
                    p = (t <= qrow_base + r) ? p : 0.f;
                    pw[(quad * 4 + r) * P_ + ts * 16 + m16] = f2bf_fast(p);
                    l_i[r] += p;
                }
            }
        } else {
            #pragma unroll
            for (int ts = 0; ts < 4; ++ts)
                #pragma unroll
                for (int r = 0; r < 4; ++r) {
                    const float p = __builtin_amdgcn_exp2f(sc[ts][r]);
                    pw[(quad * 4 + r) * P_ + ts * 16 + m16] = f2bf_fast(p);
                    l_i[r] += p;
                }
        }

        const bf16x8 pa0 = *(const bf16x8*)&pw[m16 * P_ + quad * 8];
        const bf16x8 pa1 = *(const bf16x8*)&pw[m16 * P_ + 32 + quad * 8];
        #pragma unroll
        for (int db = 0; db < 4; ++db) {
            const bf16x8 vb0 = *(const bf16x8*)&Vt[(db * 16 + m16) * P_ + quad * 8];
            const bf16x8 vb1 = *(const bf16x8*)&Vt[(db * 16 + m16) * P_ + 32 + quad * 8];
            O[db] = __builtin_amdgcn_mfma_f32_16x16x32_bf16(pa0, vb0, O[db], 0, 0, 0);
            O[db] = __builtin_amdgcn_mfma_f32_16x16x32_bf16(pa1, vb1, O[db], 0, 0, 0);
        }
    }

    #pragma unroll
    for (int off = 1; off < 16; off <<= 1)
        #pragma unroll
        for (int r = 0; r < 4; ++r)
            l_i[r] += __shfl_xor(l_i[r], off, 64);

    #pragma unroll
    for (int r = 0; r < 4; ++r) {
        const int qrow = qrow_base + r;
        if (qrow < S_) {
            const float invl = 1.0f / l_i[r];
            #pragma unroll
            for (int db = 0; db < 4; ++db)
                ybf[((size_t)b * S_ + qrow) * E_ + h * D_ + db * 16 + m16] =
                    f2bf(O[db][r] * invl);
        }
    }
}

// ---------------------------------------------------------------------------
// proj + exact GELU. R11: converted from reg-staged (P=72) single-buffer to
// gload_lds 2-phase double-buffer, same structure as qkv_mfma_kernel.
// grid (63 m, 8 n) = 504 blocks = 8 XCDs x 63 -> chunked swizzle gives each
// XCD one full n-tile (B panel 256 KB resident in its L2).
// ---------------------------------------------------------------------------
__global__ __launch_bounds__(256) void proj_mfma_kernel(
    const unsigned short* __restrict__ ybf, const unsigned short* __restrict__ wpT,
    const float* __restrict__ bp, float* __restrict__ out)
{
    __shared__ unsigned short As[2][128 * 64];
    __shared__ unsigned short Bs[2][128 * 64];

    const int tid = threadIdx.x;
    const int wave = tid >> 6, lane = tid & 63;
    const int m16 = lane & 15, quad = lane >> 4;
    const int wm = wave >> 1, wn = wave & 1;

    const int f  = (int)(blockIdx.y * gridDim.x + blockIdx.x);
    const int fp = (f & 7) * 63 + (f >> 3);
    const int m0 = (fp % 63) * 128;
    const int n0 = (fp / 63) * 128;

    f32x4 acc[4][4];
    #pragma unroll
    for (int nf = 0; nf < 4; ++nf)
        #pragma unroll
        for (int mf = 0; mf < 4; ++mf)
            acc[nf][mf] = (f32x4){0.f, 0.f, 0.f, 0.f};

    const int lrow = lane >> 3;
    const int lcol = (lane & 7) << 3;

    int a_srow[4];
    int b_srow[4];
    #pragma unroll
    for (int j = 0; j < 4; ++j) {
        int r = m0 + (wave * 4 + j) * 8 + lrow;
        a_srow[j] = (r < M_) ? r : (M_ - 1);
        b_srow[j] = n0 + (wave * 4 + j) * 8 + lrow;
    }

    #pragma unroll
    for (int j = 0; j < 4; ++j) {
        const int i = wave * 4 + j;
        gld16(ybf + (size_t)a_srow[j] * E_ + lcol, &As[0][i * 512]);
        gld16(wpT + (size_t)b_srow[j] * E_ + lcol, &Bs[0][i * 512]);
    }
    __syncthreads();

    int cur = 0;
    for (int kt = 0; kt < 16; ++kt) {
        if (kt < 15) {
            const int kn = (kt + 1) * 64;
            #pragma unroll
            for (int j = 0; j < 4; ++j) {
                const int i = wave * 4 + j;
                gld16(ybf + (size_t)a_srow[j] * E_ + kn + lcol, &As[cur ^ 1][i * 512]);
                gld16(wpT + (size_t)b_srow[j] * E_ + kn + lcol, &Bs[cur ^ 1][i * 512]);
            }
        }

        #pragma unroll
        for (int kh = 0; kh < 2; ++kh) {
            const int ko = kh * 32 + quad * 8;
            bf16x8 af[4];
            #pragma unroll
            for (int mf = 0; mf < 4; ++mf)
                af[mf] = *(const bf16x8*)&As[cur][(wm * 64 + mf * 16 + m16) * 64 + ko];
            #pragma unroll
            for (int nf = 0; nf < 4; ++nf) {
                const bf16x8 bfr = *(const bf16x8*)&Bs[cur][(wn * 64 + nf * 16 + m16) * 64 + ko];
                #pragma unroll
                for (int mf = 0; mf < 4; ++mf)
                    acc[nf][mf] = __builtin_amdgcn_mfma_f32_16x16x32_bf16(
                        af[mf], bfr, acc[nf][mf], 0, 0, 0);
            }
        }

        __syncthreads();
        cur ^= 1;
    }

    float biasv[4];
    #pragma unroll
    for (int nf = 0; nf < 4; ++nf)
        biasv[nf] = bp[n0 + wn * 64 + nf * 16 + m16];

    #pragma unroll
    for (int mf = 0; mf < 4; ++mf)
        #pragma unroll
        for (int r = 0; r < 4; ++r) {
            const int row = m0 + wm * 64 + mf * 16 + quad * 4 + r;
            if (row < M_) {
                #pragma unroll
                for (int nf = 0; nf < 4; ++nf) {
                    const int col = n0 + wn * 64 + nf * 16 + m16;
                    const float t = acc[nf][mf][r] + biasv[nf];
                    const float g = 0.5f * t * (1.0f + erff(t * 0.70710678118654752f));
                    out[(size_t)row * E_ + col] = g;
                }
            }
        }
}

// ---------------------------------------------------------------------------
extern "C" void kernel_launch(void* const* d_in, const int* in_sizes, int n_in,
                              void* d_out, int out_size, void* d_ws, size_t ws_size,
                              hipStream_t stream)
{
    const float* x  = (const float*)d_in[0];
    const float* wq = (const float*)d_in[1];
    const float* bq = (const float*)d_in[2];
    const float* wk = (const float*)d_in[3];
    const float* bk = (const float*)d_in[4];
    const float* wv = (const float*)d_in[5];
    const float* bv = (const float*)d_in[6];
    const float* wp = (const float*)d_in[7];
    const float* bp = (const float*)d_in[8];
    float* out = (float*)d_out;

    const size_t nME = (size_t)M_ * E_;          // 8,192,000
    unsigned short* xbf = (unsigned short*)d_ws;
    unsigned short* WT  = xbf + nME;             // 3,145,728
    unsigned short* wpT = WT + 3145728;          // 1,048,576
    unsigned short* qb  = wpT + 1048576;
    unsigned short* kb  = qb + nME;
    unsigned short* vb  = kb + nME;
    unsigned short* ybf = vb + nME;
    unsigned short* vtr = ybf + nME;             // v transposed [bh][d][S]

    cast_x_kernel<<<dim3((unsigned)(nME / 1024)), 256, 0, stream>>>(x, xbf);
    transpose_wqkv_kernel<<<dim3(16, 48), 256, 0, stream>>>(wq, wk, wv, WT);
    transpose_wp_kernel<<<dim3(16, 16), 256, 0, stream>>>(wp, wpT);

    // Single-GEMM qkv: grid (N-tiles=24 fastest, M-tiles=63), swizzled in-kernel.
    qkv_mfma_kernel<<<dim3(3072 / 128, (M_ + 127) / 128), 256, 0, stream>>>(
        xbf, WT, bq, bk, bv, qb, kb, vb);
    transpose_v_kernel<<<dim3(16, B_ * H_), 256, 0, stream>>>(vb, vtr);
    attn_flash_kernel<<<dim3((S_ + 63) / 64, H_, B_), 256, 0, stream>>>(
        qb, kb, vtr, ybf);
    proj_mfma_kernel<<<dim3((M_ + 127) / 128, E_ / 128), 256, 0, stream>>>(
        ybf, wpT, bp, out);
}

// Round 3
// 313.938 us; speedup vs baseline: 1.0070x; 1.0070x over previous
//
#include <hip/hip_runtime.h>
#include <hip/hip_bf16.h>
#include <math.h>

// Problem constants: B=8, S=1000, E=1024, H=16, D=64
constexpr int B_ = 8, S_ = 1000, E_ = 1024, H_ = 16, D_ = 64;
constexpr int M_ = B_ * S_;   // 8000 rows

using bf16x8 = __attribute__((ext_vector_type(8))) __bf16;
using u16x8  = __attribute__((ext_vector_type(8))) unsigned short;
using f32x4  = __attribute__((ext_vector_type(4))) float;

static __device__ __forceinline__ unsigned short f2bf(float f) {
    union { float f; unsigned u; } c; c.f = f;
    return (unsigned short)((c.u + 0x7FFF + ((c.u >> 16) & 1)) >> 16);
}
static __device__ __forceinline__ unsigned short f2bf_fast(float f) {
    union { float f; unsigned u; } c; c.f = f;
    return (unsigned short)((c.u + 0x8000) >> 16);   // round-half-up
}
static __device__ __forceinline__ float bfr2f(unsigned short s) {
    union { unsigned u; float f; } c; c.u = ((unsigned)s) << 16;
    return c.f;
}

// Async global->LDS DMA, 16B per lane. LDS dest is wave-uniform base;
// HW writes base + lane*16 (linear). Global source is per-lane.
static __device__ __forceinline__ void gld16(const unsigned short* g, unsigned short* lds) {
    __builtin_amdgcn_global_load_lds(
        (__attribute__((address_space(1))) void*)(g),
        (__attribute__((address_space(3))) void*)(lds), 16, 0, 0);
}

// ---------------------------------------------------------------------------
// Cast x (fp32 [M,E]) -> bf16.
// ---------------------------------------------------------------------------
__global__ __launch_bounds__(256) void cast_x_kernel(
    const float* __restrict__ x, unsigned short* __restrict__ xbf)
{
    const size_t i = ((size_t)blockIdx.x * 256 + threadIdx.x) * 4;
    float4 v = *(const float4*)(x + i);
    ushort4 o;
    o.x = f2bf(v.x); o.y = f2bf(v.y); o.z = f2bf(v.z); o.w = f2bf(v.w);
    *(ushort4*)(xbf + i) = o;
}

// ---------------------------------------------------------------------------
// Transpose+cast qkv weights: w[h][e][d] fp32 -> WT[(z*16+h)*64 + d][e] bf16.
// ---------------------------------------------------------------------------
__global__ __launch_bounds__(256) void transpose_wqkv_kernel(
    const float* __restrict__ wq, const float* __restrict__ wk,
    const float* __restrict__ wv, unsigned short* __restrict__ WT)
{
    __shared__ unsigned short Ts[64 * 65];
    const int et = blockIdx.x, zh = blockIdx.y;
    const int z = zh >> 4, h = zh & 15;
    const float* src = (z == 0 ? wq : z == 1 ? wk : wv) + (size_t)h * E_ * D_;

    const int d = threadIdx.x & 63;
    const int e0 = threadIdx.x >> 6;   // 0..3
    #pragma unroll
    for (int p = 0; p < 16; ++p) {
        const int e = e0 + p * 4;
        Ts[d * 65 + e] = f2bf(src[(size_t)(et * 64 + e) * D_ + d]);
    }
    __syncthreads();
    const int e = threadIdx.x & 63;
    const int d0 = threadIdx.x >> 6;
    #pragma unroll
    for (int p = 0; p < 16; ++p) {
        const int dd = d0 + p * 4;
        WT[((size_t)zh * 64 + dd) * E_ + et * 64 + e] = Ts[dd * 65 + e];
    }
}

// ---------------------------------------------------------------------------
// Transpose+cast wp: wp[e][f] fp32 -> wpT[f][e] bf16. grid (16 e, 16 f).
// ---------------------------------------------------------------------------
__global__ __launch_bounds__(256) void transpose_wp_kernel(
    const float* __restrict__ wp, unsigned short* __restrict__ wpT)
{
    __shared__ unsigned short Ts[64 * 65];
    const int et = blockIdx.x, ft = blockIdx.y;
    const int f = threadIdx.x & 63;
    const int e0 = threadIdx.x >> 6;
    #pragma unroll
    for (int p = 0; p < 16; ++p) {
        const int e = e0 + p * 4;
        Ts[f * 65 + e] = f2bf(wp[(size_t)(et * 64 + e) * E_ + ft * 64 + f]);
    }
    __syncthreads();
    const int e = threadIdx.x & 63;
    const int f0 = threadIdx.x >> 6;
    #pragma unroll
    for (int p = 0; p < 16; ++p) {
        const int ff = f0 + p * 4;
        wpT[((size_t)(ft * 64 + ff)) * E_ + et * 64 + e] = Ts[ff * 65 + e];
    }
}

// ---------------------------------------------------------------------------
// Transpose v: vb[bh][s][d] bf16 -> vt[bh][d][s] bf16. grid (16 s-tiles, 128 bh).
// ---------------------------------------------------------------------------
__global__ __launch_bounds__(256) void transpose_v_kernel(
    const unsigned short* __restrict__ vb, unsigned short* __restrict__ vt)
{
    __shared__ unsigned short Ts[64 * 65];
    const int st = blockIdx.x, bh = blockIdx.y;
    const size_t ibase = (size_t)bh * S_ * D_;
    const size_t obase = (size_t)bh * D_ * S_;

    const int d = threadIdx.x & 63;
    const int s0 = threadIdx.x >> 6;   // 0..3
    #pragma unroll
    for (int p = 0; p < 16; ++p) {
        const int s = s0 + p * 4;
        const int srow = st * 64 + s;
        Ts[s * 65 + d] = (srow < S_) ? vb[ibase + (size_t)srow * D_ + d] : 0;
    }
    __syncthreads();
    const int s = threadIdx.x & 63;
    const int d0 = threadIdx.x >> 6;
    const int scol = st * 64 + s;
    if (scol < S_) {
        #pragma unroll
        for (int p = 0; p < 16; ++p) {
            const int dd = d0 + p * 4;
            vt[obase + (size_t)dd * S_ + scol] = Ts[s * 65 + dd];
        }
    }
}

// ---------------------------------------------------------------------------
// qkv projection: ONE dense GEMM [M=8000,K=1024] x [K,N=3072].
// R12: reverted to the R10 form (proven 89.7 us, 561 TF): single-buffered,
// 2 barriers/K-tile, n-fast grid, NO xcd swizzle, NO dbuf.
// Post-mortems: R11's dbuf was drained by __syncthreads' vmcnt(0) anyway
// (m99/m100), and the chunked XCD swizzle RAISED FETCH 75->85 MB (B-panel
// thrash of per-XCD L2). 2-phase critical path = stage+drain (m233); tile
// and swizzle changes are null here. Only the 8-phase template beats this,
// but its 384-block/1-per-CU grid is 75% balanced at this shape -> shelved.
// ---------------------------------------------------------------------------
__global__ __launch_bounds__(256) void qkv_mfma_kernel(
    const unsigned short* __restrict__ xbf, const unsigned short* __restrict__ WT,
    const float* __restrict__ bq, const float* __restrict__ bk,
    const float* __restrict__ bv,
    unsigned short* __restrict__ qb, unsigned short* __restrict__ kb,
    unsigned short* __restrict__ vb)
{
    __shared__ unsigned short As[128 * 64];   // 16 KB, linear [row][64]
    __shared__ unsigned short Bs[128 * 64];   // 16 KB, linear [nrow][64]

    const int tid  = threadIdx.x;
    const int wave = tid >> 6, lane = tid & 63;
    const int m16  = lane & 15, quad = lane >> 4;
    const int wm   = wave >> 1, wn = wave & 1;
    const int n0   = blockIdx.x * 128;
    const int m0   = blockIdx.y * 128;

    f32x4 acc[4][4];   // [nf][mf]
    #pragma unroll
    for (int nf = 0; nf < 4; ++nf)
        #pragma unroll
        for (int mf = 0; mf < 4; ++mf)
            acc[nf][mf] = (f32x4){0.f, 0.f, 0.f, 0.f};

    // DMA staging coords: issue i = wave*4+j covers LDS rows 8i..8i+7;
    // lane l supplies row 8i + (l>>3), cols ((l&7)*8 .. +7).
    const int lrow = lane >> 3;          // 0..7
    const int lcol = (lane & 7) << 3;    // 0,8,..,56

    int a_srow[4];
    #pragma unroll
    for (int j = 0; j < 4; ++j) {
        int r = m0 + (wave * 4 + j) * 8 + lrow;
        a_srow[j] = (r < M_) ? r : (M_ - 1);
    }

    for (int kk = 0; kk < E_; kk += 64) {
        __syncthreads();
        #pragma unroll
        for (int j = 0; j < 4; ++j) {
            const int i = wave * 4 + j;
            gld16(xbf + (size_t)a_srow[j] * E_ + kk + lcol, &As[i * 512]);
            gld16(WT + (size_t)(n0 + i * 8 + lrow) * E_ + kk + lcol, &Bs[i * 512]);
        }
        __syncthreads();

        #pragma unroll
        for (int kh = 0; kh < 2; ++kh) {
            const int ko = kh * 32 + quad * 8;
            bf16x8 af[4];
            #pragma unroll
            for (int mf = 0; mf < 4; ++mf)
                af[mf] = *(const bf16x8*)&As[(wm * 64 + mf * 16 + m16) * 64 + ko];
            #pragma unroll
            for (int nf = 0; nf < 4; ++nf) {
                const bf16x8 bfr = *(const bf16x8*)&Bs[(wn * 64 + nf * 16 + m16) * 64 + ko];
                #pragma unroll
                for (int mf = 0; mf < 4; ++mf)
                    acc[nf][mf] = __builtin_amdgcn_mfma_f32_16x16x32_bf16(
                        af[mf], bfr, acc[nf][mf], 0, 0, 0);
            }
        }
    }

    const int z = n0 >> 10;
    const int h = ((n0 >> 6) + wn) & 15;
    unsigned short* const ob = (z == 0) ? qb : (z == 1) ? kb : vb;
    const float* const bz    = (z == 0) ? bq : (z == 1) ? bk : bv;

    float biasv[4];
    #pragma unroll
    for (int nf = 0; nf < 4; ++nf)
        biasv[nf] = bz[h * D_ + nf * 16 + m16];

    #pragma unroll
    for (int mf = 0; mf < 4; ++mf)
        #pragma unroll
        for (int r = 0; r < 4; ++r) {
            const int row = m0 + wm * 64 + mf * 16 + quad * 4 + r;
            if (row < M_) {
                const int b = row / S_, s = row % S_;
                const size_t obase = (((size_t)b * H_ + h) * S_ + s) * D_ + m16;
                #pragma unroll
                for (int nf = 0; nf < 4; ++nf)
                    ob[obase + nf * 16] = f2bf(acc[nf][mf][r] + biasv[nf]);
            }
        }
}

// ---------------------------------------------------------------------------
// Flash attention. R12: KVBLK 64 -> 128. Theory: attn is barrier/stall-bound
// (compute floor ~25 us vs ~100+ actual); halving the __syncthreads drains
// per key and doubling MFMA per barrier-pair (16->32/wave) amortizes the
// stall. LDS 61.0 KB -> still 2 blocks/CU. Padding: PK=72 (K rows, 64 cols),
// PT=136 (128-col rows of Vt/Ps) keeps the 2-way-max bank pattern.
// Causal mask still applied only on the last (diagonal) tile; keys >= S
// (1000..1023) appear only in diagonal tiles, where the causal mask
// subsumes the S-bound (max valid qrow 999 < 1000).
// ---------------------------------------------------------------------------
__global__ __launch_bounds__(256) void attn_flash_kernel(
    const unsigned short* __restrict__ q, const unsigned short* __restrict__ k,
    const unsigned short* __restrict__ vt, unsigned short* __restrict__ ybf)
{
    constexpr int PK = 72;    // pad for 64-col rows (K, Q)
    constexpr int PT = 136;   // pad for 128-col rows (Vt, Ps)
    __shared__ unsigned short Qs[64 * PK];    //  9.2 KB
    __shared__ unsigned short Ks[128 * PK];   // 18.4 KB
    __shared__ unsigned short Vt[64 * PT];    // 17.4 KB  [d][t]
    __shared__ unsigned short Ps[4][16 * PT]; // 17.4 KB

    const int tid  = threadIdx.x;
    const int wave = tid >> 6, lane = tid & 63;
    const int m16  = lane & 15, quad = lane >> 4;
    const int qt = (int)gridDim.x - 1 - (int)blockIdx.x;   // long blocks first
    const int h = blockIdx.y, b = blockIdx.z;
    const size_t bh  = ((size_t)b * H_ + h) * S_;
    const size_t vtb = ((size_t)b * H_ + h) * (size_t)D_ * S_;
    const float sl2e = 0.031622776601683794f * 1.4426950408889634f;

    const int c8 = (tid & 7) * 8;
    const int r0 = tid >> 3;        // 0..31
    const int dv = tid >> 4;        // 0..15  (V d-row)
    const int cv = (tid & 15) * 8;  // 0..120 (V t-col)

    #pragma unroll
    for (int rr = 0; rr < 64; rr += 32) {
        const int r = r0 + rr;
        const int srow = qt * 64 + r;
        u16x8 val = {0, 0, 0, 0, 0, 0, 0, 0};
        if (srow < S_) val = *(const u16x8*)(q + (bh + srow) * D_ + c8);
        u16x8 o;
        #pragma unroll
        for (int j = 0; j < 8; ++j) o[j] = f2bf_fast(bfr2f(val[j]) * sl2e);
        *(u16x8*)&Qs[r * PK + c8] = o;
    }
    __syncthreads();

    const bf16x8 qa0 = *(const bf16x8*)&Qs[(wave * 16 + m16) * PK + quad * 8];
    const bf16x8 qa1 = *(const bf16x8*)&Qs[(wave * 16 + m16) * PK + 32 + quad * 8];

    f32x4 O[4] = {{0,0,0,0},{0,0,0,0},{0,0,0,0},{0,0,0,0}};
    float l_i[4] = {0.f, 0.f, 0.f, 0.f};

    const int qrow_base = qt * 64 + wave * 16 + quad * 4;
    const int nt = (qt >> 1) + 1;   // number of 128-wide K-tiles

    // register prefetch of tile 0 (keys 0..127, all < S)
    u16x8 kreg[4], vreg[4];
    #pragma unroll
    for (int i = 0; i < 4; ++i) {
        kreg[i] = *(const u16x8*)(k + (bh + r0 + i * 32) * D_ + c8);
        vreg[i] = *(const u16x8*)(vt + vtb + (size_t)(dv + i * 16) * S_ + cv);
    }

    for (int tt = 0; tt < nt; ++tt) {
        const int t0 = tt * 128;
        __syncthreads();
        #pragma unroll
        for (int i = 0; i < 4; ++i) {
            *(u16x8*)&Ks[(r0 + i * 32) * PK + c8] = kreg[i];
            *(u16x8*)&Vt[(dv + i * 16) * PT + cv] = vreg[i];
        }
        __syncthreads();

        if (tt + 1 < nt) {
            const int nt0 = t0 + 128;
            #pragma unroll
            for (int i = 0; i < 4; ++i) {
                const int srow = nt0 + r0 + i * 32;
                u16x8 kv = {0,0,0,0,0,0,0,0}, vv = {0,0,0,0,0,0,0,0};
                if (srow < S_) kv = *(const u16x8*)(k + (bh + srow) * D_ + c8);
                if (nt0 + cv < S_)
                    vv = *(const u16x8*)(vt + vtb + (size_t)(dv + i * 16) * S_ + nt0 + cv);
                kreg[i] = kv; vreg[i] = vv;
            }
        }

        // QK^T: 16 q-rows x 128 keys per wave
        f32x4 sc[8];
        #pragma unroll
        for (int ts = 0; ts < 8; ++ts) {
            const bf16x8 kb0 = *(const bf16x8*)&Ks[(ts * 16 + m16) * PK + quad * 8];
            const bf16x8 kb1 = *(const bf16x8*)&Ks[(ts * 16 + m16) * PK + 32 + quad * 8];
            f32x4 a = {0.f, 0.f, 0.f, 0.f};
            a = __builtin_amdgcn_mfma_f32_16x16x32_bf16(qa0, kb0, a, 0, 0, 0);
            a = __builtin_amdgcn_mfma_f32_16x16x32_bf16(qa1, kb1, a, 0, 0, 0);
            sc[ts] = a;
        }

        unsigned short* const pw = &Ps[wave][0];
        if (tt == nt - 1) {
            #pragma unroll
            for (int ts = 0; ts < 8; ++ts) {
                const int t = t0 + ts * 16 + m16;
                #pragma unroll
                for (int r = 0; r < 4; ++r) {
                    float p = __builtin_amdgcn_exp2f(sc[ts][r]);
                    p = (t <= qrow_base + r) ? p : 0.f;
                    pw[(quad * 4 + r) * PT + ts * 16 + m16] = f2bf_fast(p);
                    l_i[r] += p;
                }
            }
        } else {
            #pragma unroll
            for (int ts = 0; ts < 8; ++ts)
                #pragma unroll
                for (int r = 0; r < 4; ++r) {
                    const float p = __builtin_amdgcn_exp2f(sc[ts][r]);
                    pw[(quad * 4 + r) * PT + ts * 16 + m16] = f2bf_fast(p);
                    l_i[r] += p;
                }
        }

        // PV: P[16 x 128] . V[128 x 64]
        bf16x8 pa[4];
        #pragma unroll
        for (int ks = 0; ks < 4; ++ks)
            pa[ks] = *(const bf16x8*)&pw[m16 * PT + ks * 32 + quad * 8];
        #pragma unroll
        for (int db = 0; db < 4; ++db) {
            #pragma unroll
            for (int ks = 0; ks < 4; ++ks) {
                const bf16x8 vb0 = *(const bf16x8*)&Vt[(db * 16 + m16) * PT + ks * 32 + quad * 8];
                O[db] = __builtin_amdgcn_mfma_f32_16x16x32_bf16(pa[ks], vb0, O[db], 0, 0, 0);
            }
        }
    }

    #pragma unroll
    for (int off = 1; off < 16; off <<= 1)
        #pragma unroll
        for (int r = 0; r < 4; ++r)
            l_i[r] += __shfl_xor(l_i[r], off, 64);

    #pragma unroll
    for (int r = 0; r < 4; ++r) {
        const int qrow = qrow_base + r;
        if (qrow < S_) {
            const float invl = 1.0f / l_i[r];
            #pragma unroll
            for (int db = 0; db < 4; ++db)
                ybf[((size_t)b * S_ + qrow) * E_ + h * D_ + db * 16 + m16] =
                    f2bf(O[db][r] * invl);
        }
    }
}

// ---------------------------------------------------------------------------
// proj + exact GELU, bf16 MFMA (reverted to R9/R10-proven reg-staged form).
// grid = (63, 8), block 256 = 2m x 2n waves; block tile 128x128.
// ---------------------------------------------------------------------------
__global__ __launch_bounds__(256) void proj_mfma_kernel(
    const unsigned short* __restrict__ ybf, const unsigned short* __restrict__ wpT,
    const float* __restrict__ bp, float* __restrict__ out)
{
    constexpr int P = 72;
    __shared__ unsigned short As[128 * P];
    __shared__ unsigned short Bs[128 * P];

    const int tid = threadIdx.x;
    const int wave = tid >> 6, lane = tid & 63;
    const int m16 = lane & 15, quad = lane >> 4;
    const int wm = wave >> 1, wn = wave & 1;
    const int m0 = blockIdx.x * 128;
    const int n0 = blockIdx.y * 128;

    f32x4 acc[4][4];
    #pragma unroll
    for (int nf = 0; nf < 4; ++nf)
        #pragma unroll
        for (int mf = 0; mf < 4; ++mf)
            acc[nf][mf] = (f32x4){0.f, 0.f, 0.f, 0.f};

    const int ar = tid & 31;
    const int ac8 = (tid >> 5) * 8;

    int asrow[4];
    #pragma unroll
    for (int p = 0; p < 4; ++p) {
        int r = m0 + ar + p * 32;
        asrow[p] = (r < M_) ? r : (M_ - 1);
    }

    u16x8 areg[4], breg[4];
    #pragma unroll
    for (int p = 0; p < 4; ++p) {
        areg[p] = *(const u16x8*)(ybf + (size_t)asrow[p] * E_ + ac8);
        breg[p] = *(const u16x8*)(wpT + (size_t)(n0 + ar + p * 32) * E_ + ac8);
    }

    for (int kk = 0; kk < E_; kk += 64) {
        __syncthreads();
        #pragma unroll
        for (int p = 0; p < 4; ++p) {
            *(u16x8*)&As[(ar + p * 32) * P + ac8] = areg[p];
            *(u16x8*)&Bs[(ar + p * 32) * P + ac8] = breg[p];
        }
        __syncthreads();

        if (kk + 64 < E_) {
            const int kn = kk + 64;
            #pragma unroll
            for (int p = 0; p < 4; ++p) {
                areg[p] = *(const u16x8*)(ybf + (size_t)asrow[p] * E_ + kn + ac8);
                breg[p] = *(const u16x8*)(wpT + (size_t)(n0 + ar + p * 32) * E_ + kn + ac8);
            }
        }

        #pragma unroll
        for (int kh = 0; kh < 2; ++kh) {
            const int ko = kh * 32 + quad * 8;
            bf16x8 af[4];
            #pragma unroll
            for (int mf = 0; mf < 4; ++mf)
                af[mf] = *(const bf16x8*)&As[(wm * 64 + mf * 16 + m16) * P + ko];
            #pragma unroll
            for (int nf = 0; nf < 4; ++nf) {
                const bf16x8 bfr = *(const bf16x8*)&Bs[(wn * 64 + nf * 16 + m16) * P + ko];
                #pragma unroll
                for (int mf = 0; mf < 4; ++mf)
                    acc[nf][mf] = __builtin_amdgcn_mfma_f32_16x16x32_bf16(
                        af[mf], bfr, acc[nf][mf], 0, 0, 0);
            }
        }
    }

    float biasv[4];
    #pragma unroll
    for (int nf = 0; nf < 4; ++nf)
        biasv[nf] = bp[n0 + wn * 64 + nf * 16 + m16];

    #pragma unroll
    for (int mf = 0; mf < 4; ++mf)
        #pragma unroll
        for (int r = 0; r < 4; ++r) {
            const int row = m0 + wm * 64 + mf * 16 + quad * 4 + r;
            if (row < M_) {
                #pragma unroll
                for (int nf = 0; nf < 4; ++nf) {
                    const int col = n0 + wn * 64 + nf * 16 + m16;
                    const float t = acc[nf][mf][r] + biasv[nf];
                    const float g = 0.5f * t * (1.0f + erff(t * 0.70710678118654752f));
                    out[(size_t)row * E_ + col] = g;
                }
            }
        }
}

// ---------------------------------------------------------------------------
extern "C" void kernel_launch(void* const* d_in, const int* in_sizes, int n_in,
                              void* d_out, int out_size, void* d_ws, size_t ws_size,
                              hipStream_t stream)
{
    const float* x  = (const float*)d_in[0];
    const float* wq = (const float*)d_in[1];
    const float* bq = (const float*)d_in[2];
    const float* wk = (const float*)d_in[3];
    const float* bk = (const float*)d_in[4];
    const float* wv = (const float*)d_in[5];
    const float* bv = (const float*)d_in[6];
    const float* wp = (const float*)d_in[7];
    const float* bp = (const float*)d_in[8];
    float* out = (float*)d_out;

    const size_t nME = (size_t)M_ * E_;          // 8,192,000
    unsigned short* xbf = (unsigned short*)d_ws;
    unsigned short* WT  = xbf + nME;             // 3,145,728
    unsigned short* wpT = WT + 3145728;          // 1,048,576
    unsigned short* qb  = wpT + 1048576;
    unsigned short* kb  = qb + nME;
    unsigned short* vb  = kb + nME;
    unsigned short* ybf = vb + nME;
    unsigned short* vtr = ybf + nME;             // v transposed [bh][d][S]

    cast_x_kernel<<<dim3((unsigned)(nME / 1024)), 256, 0, stream>>>(x, xbf);
    transpose_wqkv_kernel<<<dim3(16, 48), 256, 0, stream>>>(wq, wk, wv, WT);
    transpose_wp_kernel<<<dim3(16, 16), 256, 0, stream>>>(wp, wpT);

    // Single-GEMM qkv: grid (N-tiles=24 fastest, M-tiles=63).
    qkv_mfma_kernel<<<dim3(3072 / 128, (M_ + 127) / 128), 256, 0, stream>>>(
        xbf, WT, bq, bk, bv, qb, kb, vb);
    transpose_v_kernel<<<dim3(16, B_ * H_), 256, 0, stream>>>(vb, vtr);
    attn_flash_kernel<<<dim3((S_ + 63) / 64, H_, B_), 256, 0, stream>>>(
        qb, kb, vtr, ybf);
    proj_mfma_kernel<<<dim3((M_ + 127) / 128, E_ / 128), 256, 0, stream>>>(
        ybf, wpT, bp, out);
}

// Round 4
// 312.217 us; speedup vs baseline: 1.0126x; 1.0055x over previous
//
#include <hip/hip_runtime.h>
#include <hip/hip_bf16.h>
#include <math.h>

// Problem constants: B=8, S=1000, E=1024, H=16, D=64
constexpr int B_ = 8, S_ = 1000, E_ = 1024, H_ = 16, D_ = 64;
constexpr int M_ = B_ * S_;   // 8000 rows

using bf16x8 = __attribute__((ext_vector_type(8))) __bf16;
using u16x8  = __attribute__((ext_vector_type(8))) unsigned short;
using f32x4  = __attribute__((ext_vector_type(4))) float;

static __device__ __forceinline__ unsigned short f2bf(float f) {
    union { float f; unsigned u; } c; c.f = f;
    return (unsigned short)((c.u + 0x7FFF + ((c.u >> 16) & 1)) >> 16);
}
static __device__ __forceinline__ unsigned short f2bf_fast(float f) {
    union { float f; unsigned u; } c; c.f = f;
    return (unsigned short)((c.u + 0x8000) >> 16);   // round-half-up
}
static __device__ __forceinline__ float bfr2f(unsigned short s) {
    union { unsigned u; float f; } c; c.u = ((unsigned)s) << 16;
    return c.f;
}

// Async global->LDS DMA, 16B per lane. LDS dest is wave-uniform base;
// HW writes base + lane*16 (linear). Global source is per-lane.
static __device__ __forceinline__ void gld16(const unsigned short* g, unsigned short* lds) {
    __builtin_amdgcn_global_load_lds(
        (__attribute__((address_space(1))) void*)(g),
        (__attribute__((address_space(3))) void*)(lds), 16, 0, 0);
}

// ---------------------------------------------------------------------------
// Cast x (fp32 [M,E]) -> bf16.
// ---------------------------------------------------------------------------
__global__ __launch_bounds__(256) void cast_x_kernel(
    const float* __restrict__ x, unsigned short* __restrict__ xbf)
{
    const size_t i = ((size_t)blockIdx.x * 256 + threadIdx.x) * 4;
    float4 v = *(const float4*)(x + i);
    ushort4 o;
    o.x = f2bf(v.x); o.y = f2bf(v.y); o.z = f2bf(v.z); o.w = f2bf(v.w);
    *(ushort4*)(xbf + i) = o;
}

// ---------------------------------------------------------------------------
// Transpose+cast qkv weights: w[h][e][d] fp32 -> WT[(z*16+h)*64 + d][e] bf16.
// ---------------------------------------------------------------------------
__global__ __launch_bounds__(256) void transpose_wqkv_kernel(
    const float* __restrict__ wq, const float* __restrict__ wk,
    const float* __restrict__ wv, unsigned short* __restrict__ WT)
{
    __shared__ unsigned short Ts[64 * 65];
    const int et = blockIdx.x, zh = blockIdx.y;
    const int z = zh >> 4, h = zh & 15;
    const float* src = (z == 0 ? wq : z == 1 ? wk : wv) + (size_t)h * E_ * D_;

    const int d = threadIdx.x & 63;
    const int e0 = threadIdx.x >> 6;   // 0..3
    #pragma unroll
    for (int p = 0; p < 16; ++p) {
        const int e = e0 + p * 4;
        Ts[d * 65 + e] = f2bf(src[(size_t)(et * 64 + e) * D_ + d]);
    }
    __syncthreads();
    const int e = threadIdx.x & 63;
    const int d0 = threadIdx.x >> 6;
    #pragma unroll
    for (int p = 0; p < 16; ++p) {
        const int dd = d0 + p * 4;
        WT[((size_t)zh * 64 + dd) * E_ + et * 64 + e] = Ts[dd * 65 + e];
    }
}

// ---------------------------------------------------------------------------
// Transpose+cast wp: wp[e][f] fp32 -> wpT[f][e] bf16. grid (16 e, 16 f).
// ---------------------------------------------------------------------------
__global__ __launch_bounds__(256) void transpose_wp_kernel(
    const float* __restrict__ wp, unsigned short* __restrict__ wpT)
{
    __shared__ unsigned short Ts[64 * 65];
    const int et = blockIdx.x, ft = blockIdx.y;
    const int f = threadIdx.x & 63;
    const int e0 = threadIdx.x >> 6;
    #pragma unroll
    for (int p = 0; p < 16; ++p) {
        const int e = e0 + p * 4;
        Ts[f * 65 + e] = f2bf(wp[(size_t)(et * 64 + e) * E_ + ft * 64 + f]);
    }
    __syncthreads();
    const int e = threadIdx.x & 63;
    const int f0 = threadIdx.x >> 6;
    #pragma unroll
    for (int p = 0; p < 16; ++p) {
        const int ff = f0 + p * 4;
        wpT[((size_t)(ft * 64 + ff)) * E_ + et * 64 + e] = Ts[ff * 65 + e];
    }
}

// ---------------------------------------------------------------------------
// Transpose v: vb[bh][s][d] bf16 -> vt[bh][d][s] bf16. grid (16 s-tiles, 128 bh).
// ---------------------------------------------------------------------------
__global__ __launch_bounds__(256) void transpose_v_kernel(
    const unsigned short* __restrict__ vb, unsigned short* __restrict__ vt)
{
    __shared__ unsigned short Ts[64 * 65];
    const int st = blockIdx.x, bh = blockIdx.y;
    const size_t ibase = (size_t)bh * S_ * D_;
    const size_t obase = (size_t)bh * D_ * S_;

    const int d = threadIdx.x & 63;
    const int s0 = threadIdx.x >> 6;   // 0..3
    #pragma unroll
    for (int p = 0; p < 16; ++p) {
        const int s = s0 + p * 4;
        const int srow = st * 64 + s;
        Ts[s * 65 + d] = (srow < S_) ? vb[ibase + (size_t)srow * D_ + d] : 0;
    }
    __syncthreads();
    const int s = threadIdx.x & 63;
    const int d0 = threadIdx.x >> 6;
    const int scol = st * 64 + s;
    if (scol < S_) {
        #pragma unroll
        for (int p = 0; p < 16; ++p) {
            const int dd = d0 + p * 4;
            vt[obase + (size_t)dd * S_ + scol] = Ts[s * 65 + dd];
        }
    }
}

// ---------------------------------------------------------------------------
// qkv projection: ONE dense GEMM [M=8000,K=1024] x [K,N=3072].
// R13: 2-phase dbuf, NO swizzle (isolating R11's bundle). n-fast grid kept
// (FETCH 75 MB proven). Loop = {stage t+1 into buf^1; compute t from buf;
// ONE __syncthreads (own-vmcnt drain + barrier); swap}. Loads overlap the
// whole MFMA phase; 1 barrier/K-tile instead of 2. This is the T3 minimum
// 2-phase recipe (m248v2: 2ph = 1.10x over 2-barrier at K=1024).
// R11 post-mortem: its regression (104 us) bundled a chunked XCD swizzle
// that raised FETCH 75->85 MB; this round isolates dbuf-without-swizzle.
// ---------------------------------------------------------------------------
__global__ __launch_bounds__(256) void qkv_mfma_kernel(
    const unsigned short* __restrict__ xbf, const unsigned short* __restrict__ WT,
    const float* __restrict__ bq, const float* __restrict__ bk,
    const float* __restrict__ bv,
    unsigned short* __restrict__ qb, unsigned short* __restrict__ kb,
    unsigned short* __restrict__ vb)
{
    __shared__ unsigned short As[2][128 * 64];   // 32 KB
    __shared__ unsigned short Bs[2][128 * 64];   // 32 KB

    const int tid  = threadIdx.x;
    const int wave = tid >> 6, lane = tid & 63;
    const int m16  = lane & 15, quad = lane >> 4;
    const int wm   = wave >> 1, wn = wave & 1;
    const int n0   = blockIdx.x * 128;
    const int m0   = blockIdx.y * 128;

    f32x4 acc[4][4];   // [nf][mf]
    #pragma unroll
    for (int nf = 0; nf < 4; ++nf)
        #pragma unroll
        for (int mf = 0; mf < 4; ++mf)
            acc[nf][mf] = (f32x4){0.f, 0.f, 0.f, 0.f};

    // DMA staging coords: issue i = wave*4+j covers LDS rows 8i..8i+7;
    // lane l supplies row 8i + (l>>3), cols ((l&7)*8 .. +7).
    const int lrow = lane >> 3;          // 0..7
    const int lcol = (lane & 7) << 3;    // 0,8,..,56

    int a_srow[4];
    int b_srow[4];
    #pragma unroll
    for (int j = 0; j < 4; ++j) {
        int r = m0 + (wave * 4 + j) * 8 + lrow;
        a_srow[j] = (r < M_) ? r : (M_ - 1);
        b_srow[j] = n0 + (wave * 4 + j) * 8 + lrow;
    }

    // prologue: stage tile 0 into buf 0; __syncthreads drains vmcnt
    #pragma unroll
    for (int j = 0; j < 4; ++j) {
        const int i = wave * 4 + j;
        gld16(xbf + (size_t)a_srow[j] * E_ + lcol, &As[0][i * 512]);
        gld16(WT + (size_t)b_srow[j] * E_ + lcol, &Bs[0][i * 512]);
    }
    __syncthreads();

    int cur = 0;
    for (int kt = 0; kt < 16; ++kt) {
        // stage tile kt+1 into the other buffer; loads fly during MFMA
        if (kt < 15) {
            const int kn = (kt + 1) * 64;
            #pragma unroll
            for (int j = 0; j < 4; ++j) {
                const int i = wave * 4 + j;
                gld16(xbf + (size_t)a_srow[j] * E_ + kn + lcol, &As[cur ^ 1][i * 512]);
                gld16(WT + (size_t)b_srow[j] * E_ + kn + lcol, &Bs[cur ^ 1][i * 512]);
            }
        }

        // compute tile kt from buf[cur] (lgkm waits only)
        #pragma unroll
        for (int kh = 0; kh < 2; ++kh) {
            const int ko = kh * 32 + quad * 8;
            bf16x8 af[4];
            #pragma unroll
            for (int mf = 0; mf < 4; ++mf)
                af[mf] = *(const bf16x8*)&As[cur][(wm * 64 + mf * 16 + m16) * 64 + ko];
            #pragma unroll
            for (int nf = 0; nf < 4; ++nf) {
                const bf16x8 bfr = *(const bf16x8*)&Bs[cur][(wn * 64 + nf * 16 + m16) * 64 + ko];
                #pragma unroll
                for (int mf = 0; mf < 4; ++mf)
                    acc[nf][mf] = __builtin_amdgcn_mfma_f32_16x16x32_bf16(
                        af[mf], bfr, acc[nf][mf], 0, 0, 0);
            }
        }

        // one drain per tile: own buf^1 loads landed + all waves' buf reads done
        __syncthreads();
        cur ^= 1;
    }

    const int z = n0 >> 10;
    const int h = ((n0 >> 6) + wn) & 15;
    unsigned short* const ob = (z == 0) ? qb : (z == 1) ? kb : vb;
    const float* const bz    = (z == 0) ? bq : (z == 1) ? bk : bv;

    float biasv[4];
    #pragma unroll
    for (int nf = 0; nf < 4; ++nf)
        biasv[nf] = bz[h * D_ + nf * 16 + m16];

    #pragma unroll
    for (int mf = 0; mf < 4; ++mf)
        #pragma unroll
        for (int r = 0; r < 4; ++r) {
            const int row = m0 + wm * 64 + mf * 16 + quad * 4 + r;
            if (row < M_) {
                const int b = row / S_, s = row % S_;
                const size_t obase = (((size_t)b * H_ + h) * S_ + s) * D_ + m16;
                #pragma unroll
                for (int nf = 0; nf < 4; ++nf)
                    ob[obase + nf * 16] = f2bf(acc[nf][mf][r] + biasv[nf]);
            }
        }
}

// ---------------------------------------------------------------------------
// Flash attention — reverted to the R1-proven KVBLK=64 form (wall 302.5).
// KVBLK=128 (R12) regressed ~11 us: +64 VGPR of prefetch/score state and
// ~6% wasted diagonal-tile work outweighed the halved barrier count.
// ---------------------------------------------------------------------------
__global__ __launch_bounds__(256) void attn_flash_kernel(
    const unsigned short* __restrict__ q, const unsigned short* __restrict__ k,
    const unsigned short* __restrict__ vt, unsigned short* __restrict__ ybf)
{
    constexpr int P_ = 72;
    __shared__ unsigned short Qs[64 * P_];
    __shared__ unsigned short Ks[64 * P_];
    __shared__ unsigned short Vt[64 * P_];   // [d][t]
    __shared__ unsigned short Ps[4][16 * P_];

    const int tid  = threadIdx.x;
    const int wave = tid >> 6, lane = tid & 63;
    const int m16  = lane & 15, quad = lane >> 4;
    const int qt = (int)gridDim.x - 1 - (int)blockIdx.x;   // long blocks first
    const int h = blockIdx.y, b = blockIdx.z;
    const size_t bh  = ((size_t)b * H_ + h) * S_;
    const size_t vtb = ((size_t)b * H_ + h) * (size_t)D_ * S_;
    const float sl2e = 0.031622776601683794f * 1.4426950408889634f;

    const int c8 = (tid & 7) * 8;
    const int r0 = tid >> 3;   // 0..31

    #pragma unroll
    for (int rr = 0; rr < 64; rr += 32) {
        const int r = r0 + rr;
        const int srow = qt * 64 + r;
        u16x8 val = {0, 0, 0, 0, 0, 0, 0, 0};
        if (srow < S_) val = *(const u16x8*)(q + (bh + srow) * D_ + c8);
        u16x8 o;
        #pragma unroll
        for (int j = 0; j < 8; ++j) o[j] = f2bf_fast(bfr2f(val[j]) * sl2e);
        *(u16x8*)&Qs[r * P_ + c8] = o;
    }
    __syncthreads();

    const bf16x8 qa0 = *(const bf16x8*)&Qs[(wave * 16 + m16) * P_ + quad * 8];
    const bf16x8 qa1 = *(const bf16x8*)&Qs[(wave * 16 + m16) * P_ + 32 + quad * 8];

    f32x4 O[4] = {{0,0,0,0},{0,0,0,0},{0,0,0,0},{0,0,0,0}};
    float l_i[4] = {0.f, 0.f, 0.f, 0.f};

    const int qrow_base = qt * 64 + wave * 16 + quad * 4;

    u16x8 kreg[2], vreg[2];
    #pragma unroll
    for (int i = 0; i < 2; ++i) {
        const int srow = r0 + i * 32;
        kreg[i] = *(const u16x8*)(k + (bh + srow) * D_ + c8);
        vreg[i] = *(const u16x8*)(vt + vtb + (size_t)(r0 + i * 32) * S_ + c8);
    }

    for (int tt = 0; tt <= qt; ++tt) {
        const int t0 = tt * 64;
        __syncthreads();
        #pragma unroll
        for (int i = 0; i < 2; ++i) {
            *(u16x8*)&Ks[(r0 + i * 32) * P_ + c8] = kreg[i];
            *(u16x8*)&Vt[(r0 + i * 32) * P_ + c8] = vreg[i];
        }
        __syncthreads();

        if (tt < qt) {
            const int nt0 = t0 + 64;
            #pragma unroll
            for (int i = 0; i < 2; ++i) {
                const int t = r0 + i * 32;
                const int srow = nt0 + t;
                u16x8 kv = {0,0,0,0,0,0,0,0}, vv = {0,0,0,0,0,0,0,0};
                if (srow < S_) kv = *(const u16x8*)(k + (bh + srow) * D_ + c8);
                if (nt0 + c8 < S_)
                    vv = *(const u16x8*)(vt + vtb + (size_t)t * S_ + nt0 + c8);
                kreg[i] = kv; vreg[i] = vv;
            }
        }

        f32x4 sc[4];
        #pragma unroll
        for (int ts = 0; ts < 4; ++ts) {
            const bf16x8 kb0 = *(const bf16x8*)&Ks[(ts * 16 + m16) * P_ + quad * 8];
            const bf16x8 kb1 = *(const bf16x8*)&Ks[(ts * 16 + m16) * P_ + 32 + quad * 8];
            f32x4 a = {0.f, 0.f, 0.f, 0.f};
            a = __builtin_amdgcn_mfma_f32_16x16x32_bf16(qa0, kb0, a, 0, 0, 0);
            a = __builtin_amdgcn_mfma_f32_16x16x32_bf16(qa1, kb1, a, 0, 0, 0);
            sc[ts] = a;
        }

        unsigned short* const pw = &Ps[wave][0];
        if (tt == qt) {
            #pragma unroll
            for (int ts = 0; ts < 4; ++ts) {
                const int t = t0 + ts * 16 + m16;
                #pragma unroll
                for (int r = 0; r < 4; ++r) {
                    float p = __builtin_amdgcn_exp2f(sc[ts][r]);
                    p = (t <= qrow_base + r) ? p : 0.f;
                    pw[(quad * 4 + r) * P_ + ts * 16 + m16] = f2bf_fast(p);
                    l_i[r] += p;
                }
            }
        } else {
            #pragma unroll
            for (int ts = 0; ts < 4; ++ts)
                #pragma unroll
                for (int r = 0; r < 4; ++r) {
                    const float p = __builtin_amdgcn_exp2f(sc[ts][r]);
                    pw[(quad * 4 + r) * P_ + ts * 16 + m16] = f2bf_fast(p);
                    l_i[r] += p;
                }
        }

        const bf16x8 pa0 = *(const bf16x8*)&pw[m16 * P_ + quad * 8];
        const bf16x8 pa1 = *(const bf16x8*)&pw[m16 * P_ + 32 + quad * 8];
        #pragma unroll
        for (int db = 0; db < 4; ++db) {
            const bf16x8 vb0 = *(const bf16x8*)&Vt[(db * 16 + m16) * P_ + quad * 8];
            const bf16x8 vb1 = *(const bf16x8*)&Vt[(db * 16 + m16) * P_ + 32 + quad * 8];
            O[db] = __builtin_amdgcn_mfma_f32_16x16x32_bf16(pa0, vb0, O[db], 0, 0, 0);
            O[db] = __builtin_amdgcn_mfma_f32_16x16x32_bf16(pa1, vb1, O[db], 0, 0, 0);
        }
    }

    #pragma unroll
    for (int off = 1; off < 16; off <<= 1)
        #pragma unroll
        for (int r = 0; r < 4; ++r)
            l_i[r] += __shfl_xor(l_i[r], off, 64);

    #pragma unroll
    for (int r = 0; r < 4; ++r) {
        const int qrow = qrow_base + r;
        if (qrow < S_) {
            const float invl = 1.0f / l_i[r];
            #pragma unroll
            for (int db = 0; db < 4; ++db)
                ybf[((size_t)b * S_ + qrow) * E_ + h * D_ + db * 16 + m16] =
                    f2bf(O[db][r] * invl);
        }
    }
}

// ---------------------------------------------------------------------------
// proj + exact GELU, bf16 MFMA (R9/R10-proven reg-staged form, unchanged).
// grid = (63, 8), block 256 = 2m x 2n waves; block tile 128x128.
// ---------------------------------------------------------------------------
__global__ __launch_bounds__(256) void proj_mfma_kernel(
    const unsigned short* __restrict__ ybf, const unsigned short* __restrict__ wpT,
    const float* __restrict__ bp, float* __restrict__ out)
{
    constexpr int P = 72;
    __shared__ unsigned short As[128 * P];
    __shared__ unsigned short Bs[128 * P];

    const int tid = threadIdx.x;
    const int wave = tid >> 6, lane = tid & 63;
    const int m16 = lane & 15, quad = lane >> 4;
    const int wm = wave >> 1, wn = wave & 1;
    const int m0 = blockIdx.x * 128;
    const int n0 = blockIdx.y * 128;

    f32x4 acc[4][4];
    #pragma unroll
    for (int nf = 0; nf < 4; ++nf)
        #pragma unroll
        for (int mf = 0; mf < 4; ++mf)
            acc[nf][mf] = (f32x4){0.f, 0.f, 0.f, 0.f};

    const int ar = tid & 31;
    const int ac8 = (tid >> 5) * 8;

    int asrow[4];
    #pragma unroll
    for (int p = 0; p < 4; ++p) {
        int r = m0 + ar + p * 32;
        asrow[p] = (r < M_) ? r : (M_ - 1);
    }

    u16x8 areg[4], breg[4];
    #pragma unroll
    for (int p = 0; p < 4; ++p) {
        areg[p] = *(const u16x8*)(ybf + (size_t)asrow[p] * E_ + ac8);
        breg[p] = *(const u16x8*)(wpT + (size_t)(n0 + ar + p * 32) * E_ + ac8);
    }

    for (int kk = 0; kk < E_; kk += 64) {
        __syncthreads();
        #pragma unroll
        for (int p = 0; p < 4; ++p) {
            *(u16x8*)&As[(ar + p * 32) * P + ac8] = areg[p];
            *(u16x8*)&Bs[(ar + p * 32) * P + ac8] = breg[p];
        }
        __syncthreads();

        if (kk + 64 < E_) {
            const int kn = kk + 64;
            #pragma unroll
            for (int p = 0; p < 4; ++p) {
                areg[p] = *(const u16x8*)(ybf + (size_t)asrow[p] * E_ + kn + ac8);
                breg[p] = *(const u16x8*)(wpT + (size_t)(n0 + ar + p * 32) * E_ + kn + ac8);
            }
        }

        #pragma unroll
        for (int kh = 0; kh < 2; ++kh) {
            const int ko = kh * 32 + quad * 8;
            bf16x8 af[4];
            #pragma unroll
            for (int mf = 0; mf < 4; ++mf)
                af[mf] = *(const bf16x8*)&As[(wm * 64 + mf * 16 + m16) * P + ko];
            #pragma unroll
            for (int nf = 0; nf < 4; ++nf) {
                const bf16x8 bfr = *(const bf16x8*)&Bs[(wn * 64 + nf * 16 + m16) * P + ko];
                #pragma unroll
                for (int mf = 0; mf < 4; ++mf)
                    acc[nf][mf] = __builtin_amdgcn_mfma_f32_16x16x32_bf16(
                        af[mf], bfr, acc[nf][mf], 0, 0, 0);
            }
        }
    }

    float biasv[4];
    #pragma unroll
    for (int nf = 0; nf < 4; ++nf)
        biasv[nf] = bp[n0 + wn * 64 + nf * 16 + m16];

    #pragma unroll
    for (int mf = 0; mf < 4; ++mf)
        #pragma unroll
        for (int r = 0; r < 4; ++r) {
            const int row = m0 + wm * 64 + mf * 16 + quad * 4 + r;
            if (row < M_) {
                #pragma unroll
                for (int nf = 0; nf < 4; ++nf) {
                    const int col = n0 + wn * 64 + nf * 16 + m16;
                    const float t = acc[nf][mf][r] + biasv[nf];
                    const float g = 0.5f * t * (1.0f + erff(t * 0.70710678118654752f));
                    out[(size_t)row * E_ + col] = g;
                }
            }
        }
}

// ---------------------------------------------------------------------------
extern "C" void kernel_launch(void* const* d_in, const int* in_sizes, int n_in,
                              void* d_out, int out_size, void* d_ws, size_t ws_size,
                              hipStream_t stream)
{
    const float* x  = (const float*)d_in[0];
    const float* wq = (const float*)d_in[1];
    const float* bq = (const float*)d_in[2];
    const float* wk = (const float*)d_in[3];
    const float* bk = (const float*)d_in[4];
    const float* wv = (const float*)d_in[5];
    const float* bv = (const float*)d_in[6];
    const float* wp = (const float*)d_in[7];
    const float* bp = (const float*)d_in[8];
    float* out = (float*)d_out;

    const size_t nME = (size_t)M_ * E_;          // 8,192,000
    unsigned short* xbf = (unsigned short*)d_ws;
    unsigned short* WT  = xbf + nME;             // 3,145,728
    unsigned short* wpT = WT + 3145728;          // 1,048,576
    unsigned short* qb  = wpT + 1048576;
    unsigned short* kb  = qb + nME;
    unsigned short* vb  = kb + nME;
    unsigned short* ybf = vb + nME;
    unsigned short* vtr = ybf + nME;             // v transposed [bh][d][S]

    cast_x_kernel<<<dim3((unsigned)(nME / 1024)), 256, 0, stream>>>(x, xbf);
    transpose_wqkv_kernel<<<dim3(16, 48), 256, 0, stream>>>(wq, wk, wv, WT);
    transpose_wp_kernel<<<dim3(16, 16), 256, 0, stream>>>(wp, wpT);

    // Single-GEMM qkv: grid (N-tiles=24 fastest, M-tiles=63).
    qkv_mfma_kernel<<<dim3(3072 / 128, (M_ + 127) / 128), 256, 0, stream>>>(
        xbf, WT, bq, bk, bv, qb, kb, vb);
    transpose_v_kernel<<<dim3(16, B_ * H_), 256, 0, stream>>>(vb, vtr);
    attn_flash_kernel<<<dim3((S_ + 63) / 64, H_, B_), 256, 0, stream>>>(
        qb, kb, vtr, ybf);
    proj_mfma_kernel<<<dim3((M_ + 127) / 128, E_ / 128), 256, 0, stream>>>(
        ybf, wpT, bp, out);
}

// Round 5
// 298.306 us; speedup vs baseline: 1.0598x; 1.0466x over previous
//
#include <hip/hip_runtime.h>
#include <hip/hip_bf16.h>
#include <math.h>

// Problem constants: B=8, S=1000, E=1024, H=16, D=64
constexpr int B_ = 8, S_ = 1000, E_ = 1024, H_ = 16, D_ = 64;
constexpr int M_ = B_ * S_;   // 8000 rows

using bf16x8 = __attribute__((ext_vector_type(8))) __bf16;
using u16x8  = __attribute__((ext_vector_type(8))) unsigned short;
using f32x4  = __attribute__((ext_vector_type(4))) float;

static __device__ __forceinline__ unsigned short f2bf(float f) {
    union { float f; unsigned u; } c; c.f = f;
    return (unsigned short)((c.u + 0x7FFF + ((c.u >> 16) & 1)) >> 16);
}
static __device__ __forceinline__ unsigned short f2bf_fast(float f) {
    union { float f; unsigned u; } c; c.f = f;
    return (unsigned short)((c.u + 0x8000) >> 16);   // round-half-up
}
static __device__ __forceinline__ float bfr2f(unsigned short s) {
    union { unsigned u; float f; } c; c.u = ((unsigned)s) << 16;
    return c.f;
}

// Async global->LDS DMA, 16B per lane. LDS dest is wave-uniform base;
// HW writes base + lane*16 (linear). Global source is per-lane.
static __device__ __forceinline__ void gld16(const unsigned short* g, unsigned short* lds) {
    __builtin_amdgcn_global_load_lds(
        (__attribute__((address_space(1))) void*)(g),
        (__attribute__((address_space(3))) void*)(lds), 16, 0, 0);
}

// ---------------------------------------------------------------------------
// Cast x (fp32 [M,E]) -> bf16.
// ---------------------------------------------------------------------------
__global__ __launch_bounds__(256) void cast_x_kernel(
    const float* __restrict__ x, unsigned short* __restrict__ xbf)
{
    const size_t i = ((size_t)blockIdx.x * 256 + threadIdx.x) * 4;
    float4 v = *(const float4*)(x + i);
    ushort4 o;
    o.x = f2bf(v.x); o.y = f2bf(v.y); o.z = f2bf(v.z); o.w = f2bf(v.w);
    *(ushort4*)(xbf + i) = o;
}

// ---------------------------------------------------------------------------
// Transpose+cast qkv weights: w[h][e][d] fp32 -> WT[(z*16+h)*64 + d][e] bf16.
// ---------------------------------------------------------------------------
__global__ __launch_bounds__(256) void transpose_wqkv_kernel(
    const float* __restrict__ wq, const float* __restrict__ wk,
    const float* __restrict__ wv, unsigned short* __restrict__ WT)
{
    __shared__ unsigned short Ts[64 * 65];
    const int et = blockIdx.x, zh = blockIdx.y;
    const int z = zh >> 4, h = zh & 15;
    const float* src = (z == 0 ? wq : z == 1 ? wk : wv) + (size_t)h * E_ * D_;

    const int d = threadIdx.x & 63;
    const int e0 = threadIdx.x >> 6;   // 0..3
    #pragma unroll
    for (int p = 0; p < 16; ++p) {
        const int e = e0 + p * 4;
        Ts[d * 65 + e] = f2bf(src[(size_t)(et * 64 + e) * D_ + d]);
    }
    __syncthreads();
    const int e = threadIdx.x & 63;
    const int d0 = threadIdx.x >> 6;
    #pragma unroll
    for (int p = 0; p < 16; ++p) {
        const int dd = d0 + p * 4;
        WT[((size_t)zh * 64 + dd) * E_ + et * 64 + e] = Ts[dd * 65 + e];
    }
}

// ---------------------------------------------------------------------------
// Transpose+cast wp: wp[e][f] fp32 -> wpT[f][e] bf16. grid (16 e, 16 f).
// ---------------------------------------------------------------------------
__global__ __launch_bounds__(256) void transpose_wp_kernel(
    const float* __restrict__ wp, unsigned short* __restrict__ wpT)
{
    __shared__ unsigned short Ts[64 * 65];
    const int et = blockIdx.x, ft = blockIdx.y;
    const int f = threadIdx.x & 63;
    const int e0 = threadIdx.x >> 6;
    #pragma unroll
    for (int p = 0; p < 16; ++p) {
        const int e = e0 + p * 4;
        Ts[f * 65 + e] = f2bf(wp[(size_t)(et * 64 + e) * E_ + ft * 64 + f]);
    }
    __syncthreads();
    const int e = threadIdx.x & 63;
    const int f0 = threadIdx.x >> 6;
    #pragma unroll
    for (int p = 0; p < 16; ++p) {
        const int ff = f0 + p * 4;
        wpT[((size_t)(ft * 64 + ff)) * E_ + et * 64 + e] = Ts[ff * 65 + e];
    }
}

// ---------------------------------------------------------------------------
// Transpose v: vb[bh][s][d] bf16 -> vt[bh][d][s] bf16. grid (16 s-tiles, 128 bh).
// ---------------------------------------------------------------------------
__global__ __launch_bounds__(256) void transpose_v_kernel(
    const unsigned short* __restrict__ vb, unsigned short* __restrict__ vt)
{
    __shared__ unsigned short Ts[64 * 65];
    const int st = blockIdx.x, bh = blockIdx.y;
    const size_t ibase = (size_t)bh * S_ * D_;
    const size_t obase = (size_t)bh * D_ * S_;

    const int d = threadIdx.x & 63;
    const int s0 = threadIdx.x >> 6;   // 0..3
    #pragma unroll
    for (int p = 0; p < 16; ++p) {
        const int s = s0 + p * 4;
        const int srow = st * 64 + s;
        Ts[s * 65 + d] = (srow < S_) ? vb[ibase + (size_t)srow * D_ + d] : 0;
    }
    __syncthreads();
    const int s = threadIdx.x & 63;
    const int d0 = threadIdx.x >> 6;
    const int scol = st * 64 + s;
    if (scol < S_) {
        #pragma unroll
        for (int p = 0; p < 16; ++p) {
            const int dd = d0 + p * 4;
            vt[obase + (size_t)dd * S_ + scol] = Ts[s * 65 + dd];
        }
    }
}

// ---------------------------------------------------------------------------
// qkv projection: ONE dense GEMM [M=8000,K=1024] x [K,N=3072].
// FINAL STRUCTURE (R14): 2-barrier single-buffer m97 form, n-fast grid.
// Measured ladder on this kernel: 2-barrier 90.6 us / MfmaUtil 23 (best);
// 2ph-dbuf-noswz 97.9; 2ph+XCD-swz 104 (swizzle thrashes per-XCD L2,
// FETCH 75->85 MB). Single-sync 2-phase still drains vmcnt(0) at the
// barrier (m233) -- moved the wait, didn't shrink it, cost 2x LDS.
// Do NOT revisit dbuf/swizzle here. 8-phase 256^2 shelved: 75% load
// balance at this shape + blind-port risk (m232 failure precedent).
// ---------------------------------------------------------------------------
__global__ __launch_bounds__(256) void qkv_mfma_kernel(
    const unsigned short* __restrict__ xbf, const unsigned short* __restrict__ WT,
    const float* __restrict__ bq, const float* __restrict__ bk,
    const float* __restrict__ bv,
    unsigned short* __restrict__ qb, unsigned short* __restrict__ kb,
    unsigned short* __restrict__ vb)
{
    __shared__ unsigned short As[128 * 64];   // 16 KB, linear [row][64]
    __shared__ unsigned short Bs[128 * 64];   // 16 KB, linear [nrow][64]

    const int tid  = threadIdx.x;
    const int wave = tid >> 6, lane = tid & 63;
    const int m16  = lane & 15, quad = lane >> 4;
    const int wm   = wave >> 1, wn = wave & 1;
    const int n0   = blockIdx.x * 128;
    const int m0   = blockIdx.y * 128;

    f32x4 acc[4][4];   // [nf][mf]
    #pragma unroll
    for (int nf = 0; nf < 4; ++nf)
        #pragma unroll
        for (int mf = 0; mf < 4; ++mf)
            acc[nf][mf] = (f32x4){0.f, 0.f, 0.f, 0.f};

    // DMA staging coords: issue i = wave*4+j covers LDS rows 8i..8i+7;
    // lane l supplies row 8i + (l>>3), cols ((l&7)*8 .. +7).
    const int lrow = lane >> 3;          // 0..7
    const int lcol = (lane & 7) << 3;    // 0,8,..,56

    int a_srow[4];
    #pragma unroll
    for (int j = 0; j < 4; ++j) {
        int r = m0 + (wave * 4 + j) * 8 + lrow;
        a_srow[j] = (r < M_) ? r : (M_ - 1);
    }

    for (int kk = 0; kk < E_; kk += 64) {
        __syncthreads();
        #pragma unroll
        for (int j = 0; j < 4; ++j) {
            const int i = wave * 4 + j;
            gld16(xbf + (size_t)a_srow[j] * E_ + kk + lcol, &As[i * 512]);
            gld16(WT + (size_t)(n0 + i * 8 + lrow) * E_ + kk + lcol, &Bs[i * 512]);
        }
        __syncthreads();

        #pragma unroll
        for (int kh = 0; kh < 2; ++kh) {
            const int ko = kh * 32 + quad * 8;
            bf16x8 af[4];
            #pragma unroll
            for (int mf = 0; mf < 4; ++mf)
                af[mf] = *(const bf16x8*)&As[(wm * 64 + mf * 16 + m16) * 64 + ko];
            #pragma unroll
            for (int nf = 0; nf < 4; ++nf) {
                const bf16x8 bfr = *(const bf16x8*)&Bs[(wn * 64 + nf * 16 + m16) * 64 + ko];
                #pragma unroll
                for (int mf = 0; mf < 4; ++mf)
                    acc[nf][mf] = __builtin_amdgcn_mfma_f32_16x16x32_bf16(
                        af[mf], bfr, acc[nf][mf], 0, 0, 0);
            }
        }
    }

    const int z = n0 >> 10;
    const int h = ((n0 >> 6) + wn) & 15;
    unsigned short* const ob = (z == 0) ? qb : (z == 1) ? kb : vb;
    const float* const bz    = (z == 0) ? bq : (z == 1) ? bk : bv;

    float biasv[4];
    #pragma unroll
    for (int nf = 0; nf < 4; ++nf)
        biasv[nf] = bz[h * D_ + nf * 16 + m16];

    #pragma unroll
    for (int mf = 0; mf < 4; ++mf)
        #pragma unroll
        for (int r = 0; r < 4; ++r) {
            const int row = m0 + wm * 64 + mf * 16 + quad * 4 + r;
            if (row < M_) {
                const int b = row / S_, s = row % S_;
                const size_t obase = (((size_t)b * H_ + h) * S_ + s) * D_ + m16;
                #pragma unroll
                for (int nf = 0; nf < 4; ++nf)
                    ob[obase + nf * 16] = f2bf(acc[nf][mf][r] + biasv[nf]);
            }
        }
}

// ---------------------------------------------------------------------------
// Flash attention, KVBLK=64 (R1-proven) + T5 setprio around MFMA clusters
// (m191: +4-7% attn, within-probe A/B; attn is multi-block latency-bound,
// the regime where setprio pays -- unlike barrier-locked GEMM, m190 null).
// KVBLK=128 regressed (R12: +64 VGPR state, wasted diagonal work).
// ---------------------------------------------------------------------------
__global__ __launch_bounds__(256) void attn_flash_kernel(
    const unsigned short* __restrict__ q, const unsigned short* __restrict__ k,
    const unsigned short* __restrict__ vt, unsigned short* __restrict__ ybf)
{
    constexpr int P_ = 72;
    __shared__ unsigned short Qs[64 * P_];
    __shared__ unsigned short Ks[64 * P_];
    __shared__ unsigned short Vt[64 * P_];   // [d][t]
    __shared__ unsigned short Ps[4][16 * P_];

    const int tid  = threadIdx.x;
    const int wave = tid >> 6, lane = tid & 63;
    const int m16  = lane & 15, quad = lane >> 4;
    const int qt = (int)gridDim.x - 1 - (int)blockIdx.x;   // long blocks first
    const int h = blockIdx.y, b = blockIdx.z;
    const size_t bh  = ((size_t)b * H_ + h) * S_;
    const size_t vtb = ((size_t)b * H_ + h) * (size_t)D_ * S_;
    const float sl2e = 0.031622776601683794f * 1.4426950408889634f;

    const int c8 = (tid & 7) * 8;
    const int r0 = tid >> 3;   // 0..31

    #pragma unroll
    for (int rr = 0; rr < 64; rr += 32) {
        const int r = r0 + rr;
        const int srow = qt * 64 + r;
        u16x8 val = {0, 0, 0, 0, 0, 0, 0, 0};
        if (srow < S_) val = *(const u16x8*)(q + (bh + srow) * D_ + c8);
        u16x8 o;
        #pragma unroll
        for (int j = 0; j < 8; ++j) o[j] = f2bf_fast(bfr2f(val[j]) * sl2e);
        *(u16x8*)&Qs[r * P_ + c8] = o;
    }
    __syncthreads();

    const bf16x8 qa0 = *(const bf16x8*)&Qs[(wave * 16 + m16) * P_ + quad * 8];
    const bf16x8 qa1 = *(const bf16x8*)&Qs[(wave * 16 + m16) * P_ + 32 + quad * 8];

    f32x4 O[4] = {{0,0,0,0},{0,0,0,0},{0,0,0,0},{0,0,0,0}};
    float l_i[4] = {0.f, 0.f, 0.f, 0.f};

    const int qrow_base = qt * 64 + wave * 16 + quad * 4;

    u16x8 kreg[2], vreg[2];
    #pragma unroll
    for (int i = 0; i < 2; ++i) {
        const int srow = r0 + i * 32;
        kreg[i] = *(const u16x8*)(k + (bh + srow) * D_ + c8);
        vreg[i] = *(const u16x8*)(vt + vtb + (size_t)(r0 + i * 32) * S_ + c8);
    }

    for (int tt = 0; tt <= qt; ++tt) {
        const int t0 = tt * 64;
        __syncthreads();
        #pragma unroll
        for (int i = 0; i < 2; ++i) {
            *(u16x8*)&Ks[(r0 + i * 32) * P_ + c8] = kreg[i];
            *(u16x8*)&Vt[(r0 + i * 32) * P_ + c8] = vreg[i];
        }
        __syncthreads();

        if (tt < qt) {
            const int nt0 = t0 + 64;
            #pragma unroll
            for (int i = 0; i < 2; ++i) {
                const int t = r0 + i * 32;
                const int srow = nt0 + t;
                u16x8 kv = {0,0,0,0,0,0,0,0}, vv = {0,0,0,0,0,0,0,0};
                if (srow < S_) kv = *(const u16x8*)(k + (bh + srow) * D_ + c8);
                if (nt0 + c8 < S_)
                    vv = *(const u16x8*)(vt + vtb + (size_t)t * S_ + nt0 + c8);
                kreg[i] = kv; vreg[i] = vv;
            }
        }

        f32x4 sc[4];
        __builtin_amdgcn_s_setprio(1);
        #pragma unroll
        for (int ts = 0; ts < 4; ++ts) {
            const bf16x8 kb0 = *(const bf16x8*)&Ks[(ts * 16 + m16) * P_ + quad * 8];
            const bf16x8 kb1 = *(const bf16x8*)&Ks[(ts * 16 + m16) * P_ + 32 + quad * 8];
            f32x4 a = {0.f, 0.f, 0.f, 0.f};
            a = __builtin_amdgcn_mfma_f32_16x16x32_bf16(qa0, kb0, a, 0, 0, 0);
            a = __builtin_amdgcn_mfma_f32_16x16x32_bf16(qa1, kb1, a, 0, 0, 0);
            sc[ts] = a;
        }
        __builtin_amdgcn_s_setprio(0);

        unsigned short* const pw = &Ps[wave][0];
        if (tt == qt) {
            #pragma unroll
            for (int ts = 0; ts < 4; ++ts) {
                const int t = t0 + ts * 16 + m16;
                #pragma unroll
                for (int r = 0; r < 4; ++r) {
                    float p = __builtin_amdgcn_exp2f(sc[ts][r]);
                    p = (t <= qrow_base + r) ? p : 0.f;
                    pw[(quad * 4 + r) * P_ + ts * 16 + m16] = f2bf_fast(p);
                    l_i[r] += p;
                }
            }
        } else {
            #pragma unroll
            for (int ts = 0; ts < 4; ++ts)
                #pragma unroll
                for (int r = 0; r < 4; ++r) {
                    const float p = __builtin_amdgcn_exp2f(sc[ts][r]);
                    pw[(quad * 4 + r) * P_ + ts * 16 + m16] = f2bf_fast(p);
                    l_i[r] += p;
                }
        }

        const bf16x8 pa0 = *(const bf16x8*)&pw[m16 * P_ + quad * 8];
        const bf16x8 pa1 = *(const bf16x8*)&pw[m16 * P_ + 32 + quad * 8];
        __builtin_amdgcn_s_setprio(1);
        #pragma unroll
        for (int db = 0; db < 4; ++db) {
            const bf16x8 vb0 = *(const bf16x8*)&Vt[(db * 16 + m16) * P_ + quad * 8];
            const bf16x8 vb1 = *(const bf16x8*)&Vt[(db * 16 + m16) * P_ + 32 + quad * 8];
            O[db] = __builtin_amdgcn_mfma_f32_16x16x32_bf16(pa0, vb0, O[db], 0, 0, 0);
            O[db] = __builtin_amdgcn_mfma_f32_16x16x32_bf16(pa1, vb1, O[db], 0, 0, 0);
        }
        __builtin_amdgcn_s_setprio(0);
    }

    #pragma unroll
    for (int off = 1; off < 16; off <<= 1)
        #pragma unroll
        for (int r = 0; r < 4; ++r)
            l_i[r] += __shfl_xor(l_i[r], off, 64);

    #pragma unroll
    for (int r = 0; r < 4; ++r) {
        const int qrow = qrow_base + r;
        if (qrow < S_) {
            const float invl = 1.0f / l_i[r];
            #pragma unroll
            for (int db = 0; db < 4; ++db)
                ybf[((size_t)b * S_ + qrow) * E_ + h * D_ + db * 16 + m16] =
                    f2bf(O[db][r] * invl);
        }
    }
}

// ---------------------------------------------------------------------------
// proj + exact GELU. R14: converted reg-staged (P=72) -> m97 gload_lds
// 2-barrier single-buffer -- the EXACT structure that measured best on qkv
// (90.6 us / 561 TF). m151: gload_lds 874 vs reg-staged 646 TF at 128^2.
// (R2's proj gload_lds test was bundled with dbuf+swizzle and came out
// neutral; this isolates the clean form.) grid (63 m-fast, 8 n): 63
// consecutive blocks share one 256 KB B-panel -> L2-friendly.
// ---------------------------------------------------------------------------
__global__ __launch_bounds__(256) void proj_mfma_kernel(
    const unsigned short* __restrict__ ybf, const unsigned short* __restrict__ wpT,
    const float* __restrict__ bp, float* __restrict__ out)
{
    __shared__ unsigned short As[128 * 64];   // 16 KB, linear
    __shared__ unsigned short Bs[128 * 64];   // 16 KB, linear

    const int tid = threadIdx.x;
    const int wave = tid >> 6, lane = tid & 63;
    const int m16 = lane & 15, quad = lane >> 4;
    const int wm = wave >> 1, wn = wave & 1;
    const int m0 = blockIdx.x * 128;
    const int n0 = blockIdx.y * 128;

    f32x4 acc[4][4];
    #pragma unroll
    for (int nf = 0; nf < 4; ++nf)
        #pragma unroll
        for (int mf = 0; mf < 4; ++mf)
            acc[nf][mf] = (f32x4){0.f, 0.f, 0.f, 0.f};

    const int lrow = lane >> 3;          // 0..7
    const int lcol = (lane & 7) << 3;    // 0,8,..,56

    int a_srow[4];
    #pragma unroll
    for (int j = 0; j < 4; ++j) {
        int r = m0 + (wave * 4 + j) * 8 + lrow;
        a_srow[j] = (r < M_) ? r : (M_ - 1);
    }

    for (int kk = 0; kk < E_; kk += 64) {
        __syncthreads();
        #pragma unroll
        for (int j = 0; j < 4; ++j) {
            const int i = wave * 4 + j;
            gld16(ybf + (size_t)a_srow[j] * E_ + kk + lcol, &As[i * 512]);
            gld16(wpT + (size_t)(n0 + i * 8 + lrow) * E_ + kk + lcol, &Bs[i * 512]);
        }
        __syncthreads();

        #pragma unroll
        for (int kh = 0; kh < 2; ++kh) {
            const int ko = kh * 32 + quad * 8;
            bf16x8 af[4];
            #pragma unroll
            for (int mf = 0; mf < 4; ++mf)
                af[mf] = *(const bf16x8*)&As[(wm * 64 + mf * 16 + m16) * 64 + ko];
            #pragma unroll
            for (int nf = 0; nf < 4; ++nf) {
                const bf16x8 bfr = *(const bf16x8*)&Bs[(wn * 64 + nf * 16 + m16) * 64 + ko];
                #pragma unroll
                for (int mf = 0; mf < 4; ++mf)
                    acc[nf][mf] = __builtin_amdgcn_mfma_f32_16x16x32_bf16(
                        af[mf], bfr, acc[nf][mf], 0, 0, 0);
            }
        }
    }

    float biasv[4];
    #pragma unroll
    for (int nf = 0; nf < 4; ++nf)
        biasv[nf] = bp[n0 + wn * 64 + nf * 16 + m16];

    #pragma unroll
    for (int mf = 0; mf < 4; ++mf)
        #pragma unroll
        for (int r = 0; r < 4; ++r) {
            const int row = m0 + wm * 64 + mf * 16 + quad * 4 + r;
            if (row < M_) {
                #pragma unroll
                for (int nf = 0; nf < 4; ++nf) {
                    const int col = n0 + wn * 64 + nf * 16 + m16;
                    const float t = acc[nf][mf][r] + biasv[nf];
                    const float g = 0.5f * t * (1.0f + erff(t * 0.70710678118654752f));
                    out[(size_t)row * E_ + col] = g;
                }
            }
        }
}

// ---------------------------------------------------------------------------
extern "C" void kernel_launch(void* const* d_in, const int* in_sizes, int n_in,
                              void* d_out, int out_size, void* d_ws, size_t ws_size,
                              hipStream_t stream)
{
    const float* x  = (const float*)d_in[0];
    const float* wq = (const float*)d_in[1];
    const float* bq = (const float*)d_in[2];
    const float* wk = (const float*)d_in[3];
    const float* bk = (const float*)d_in[4];
    const float* wv = (const float*)d_in[5];
    const float* bv = (const float*)d_in[6];
    const float* wp = (const float*)d_in[7];
    const float* bp = (const float*)d_in[8];
    float* out = (float*)d_out;

    const size_t nME = (size_t)M_ * E_;          // 8,192,000
    unsigned short* xbf = (unsigned short*)d_ws;
    unsigned short* WT  = xbf + nME;             // 3,145,728
    unsigned short* wpT = WT + 3145728;          // 1,048,576
    unsigned short* qb  = wpT + 1048576;
    unsigned short* kb  = qb + nME;
    unsigned short* vb  = kb + nME;
    unsigned short* ybf = vb + nME;
    unsigned short* vtr = ybf + nME;             // v transposed [bh][d][S]

    cast_x_kernel<<<dim3((unsigned)(nME / 1024)), 256, 0, stream>>>(x, xbf);
    transpose_wqkv_kernel<<<dim3(16, 48), 256, 0, stream>>>(wq, wk, wv, WT);
    transpose_wp_kernel<<<dim3(16, 16), 256, 0, stream>>>(wp, wpT);

    // Single-GEMM qkv: grid (N-tiles=24 fastest, M-tiles=63).
    qkv_mfma_kernel<<<dim3(3072 / 128, (M_ + 127) / 128), 256, 0, stream>>>(
        xbf, WT, bq, bk, bv, qb, kb, vb);
    transpose_v_kernel<<<dim3(16, B_ * H_), 256, 0, stream>>>(vb, vtr);
    attn_flash_kernel<<<dim3((S_ + 63) / 64, H_, B_), 256, 0, stream>>>(
        qb, kb, vtr, ybf);
    proj_mfma_kernel<<<dim3((M_ + 127) / 128, E_ / 128), 256, 0, stream>>>(
        ybf, wpT, bp, out);
}

// Round 6
// 288.836 us; speedup vs baseline: 1.0945x; 1.0328x over previous
//
#include <hip/hip_runtime.h>
#include <hip/hip_bf16.h>
#include <math.h>

// Problem constants: B=8, S=1000, E=1024, H=16, D=64
constexpr int B_ = 8, S_ = 1000, E_ = 1024, H_ = 16, D_ = 64;
constexpr int M_ = B_ * S_;   // 8000 rows

using bf16x8 = __attribute__((ext_vector_type(8))) __bf16;
using u16x8  = __attribute__((ext_vector_type(8))) unsigned short;
using f32x4  = __attribute__((ext_vector_type(4))) float;

static __device__ __forceinline__ unsigned short f2bf(float f) {
    union { float f; unsigned u; } c; c.f = f;
    return (unsigned short)((c.u + 0x7FFF + ((c.u >> 16) & 1)) >> 16);
}
static __device__ __forceinline__ unsigned short f2bf_fast(float f) {
    union { float f; unsigned u; } c; c.f = f;
    return (unsigned short)((c.u + 0x8000) >> 16);   // round-half-up
}
static __device__ __forceinline__ float bfr2f(unsigned short s) {
    union { unsigned u; float f; } c; c.u = ((unsigned)s) << 16;
    return c.f;
}

// Async global->LDS DMA, 16B per lane. LDS dest is wave-uniform base;
// HW writes base + lane*16 (linear). Global source is per-lane.
static __device__ __forceinline__ void gld16(const unsigned short* g, unsigned short* lds) {
    __builtin_amdgcn_global_load_lds(
        (__attribute__((address_space(1))) void*)(g),
        (__attribute__((address_space(3))) void*)(lds), 16, 0, 0);
}

// ---------------------------------------------------------------------------
// Cast x (fp32 [M,E]) -> bf16.
// ---------------------------------------------------------------------------
__global__ __launch_bounds__(256) void cast_x_kernel(
    const float* __restrict__ x, unsigned short* __restrict__ xbf)
{
    const size_t i = ((size_t)blockIdx.x * 256 + threadIdx.x) * 4;
    float4 v = *(const float4*)(x + i);
    ushort4 o;
    o.x = f2bf(v.x); o.y = f2bf(v.y); o.z = f2bf(v.z); o.w = f2bf(v.w);
    *(ushort4*)(xbf + i) = o;
}

// ---------------------------------------------------------------------------
// Transpose+cast qkv weights: w[h][e][d] fp32 -> WT[(z*16+h)*64 + d][e] bf16.
// ---------------------------------------------------------------------------
__global__ __launch_bounds__(256) void transpose_wqkv_kernel(
    const float* __restrict__ wq, const float* __restrict__ wk,
    const float* __restrict__ wv, unsigned short* __restrict__ WT)
{
    __shared__ unsigned short Ts[64 * 65];
    const int et = blockIdx.x, zh = blockIdx.y;
    const int z = zh >> 4, h = zh & 15;
    const float* src = (z == 0 ? wq : z == 1 ? wk : wv) + (size_t)h * E_ * D_;

    const int d = threadIdx.x & 63;
    const int e0 = threadIdx.x >> 6;   // 0..3
    #pragma unroll
    for (int p = 0; p < 16; ++p) {
        const int e = e0 + p * 4;
        Ts[d * 65 + e] = f2bf(src[(size_t)(et * 64 + e) * D_ + d]);
    }
    __syncthreads();
    const int e = threadIdx.x & 63;
    const int d0 = threadIdx.x >> 6;
    #pragma unroll
    for (int p = 0; p < 16; ++p) {
        const int dd = d0 + p * 4;
        WT[((size_t)zh * 64 + dd) * E_ + et * 64 + e] = Ts[dd * 65 + e];
    }
}

// ---------------------------------------------------------------------------
// Transpose+cast wp: wp[e][f] fp32 -> wpT[f][e] bf16. grid (16 e, 16 f).
// ---------------------------------------------------------------------------
__global__ __launch_bounds__(256) void transpose_wp_kernel(
    const float* __restrict__ wp, unsigned short* __restrict__ wpT)
{
    __shared__ unsigned short Ts[64 * 65];
    const int et = blockIdx.x, ft = blockIdx.y;
    const int f = threadIdx.x & 63;
    const int e0 = threadIdx.x >> 6;
    #pragma unroll
    for (int p = 0; p < 16; ++p) {
        const int e = e0 + p * 4;
        Ts[f * 65 + e] = f2bf(wp[(size_t)(et * 64 + e) * E_ + ft * 64 + f]);
    }
    __syncthreads();
    const int e = threadIdx.x & 63;
    const int f0 = threadIdx.x >> 6;
    #pragma unroll
    for (int p = 0; p < 16; ++p) {
        const int ff = f0 + p * 4;
        wpT[((size_t)(ft * 64 + ff)) * E_ + et * 64 + e] = Ts[ff * 65 + e];
    }
}

// ---------------------------------------------------------------------------
// Transpose v: vb[bh][s][d] bf16 -> vt[bh][d][s] bf16. grid (16 s-tiles, 128 bh).
// ---------------------------------------------------------------------------
__global__ __launch_bounds__(256) void transpose_v_kernel(
    const unsigned short* __restrict__ vb, unsigned short* __restrict__ vt)
{
    __shared__ unsigned short Ts[64 * 65];
    const int st = blockIdx.x, bh = blockIdx.y;
    const size_t ibase = (size_t)bh * S_ * D_;
    const size_t obase = (size_t)bh * D_ * S_;

    const int d = threadIdx.x & 63;
    const int s0 = threadIdx.x >> 6;   // 0..3
    #pragma unroll
    for (int p = 0; p < 16; ++p) {
        const int s = s0 + p * 4;
        const int srow = st * 64 + s;
        Ts[s * 65 + d] = (srow < S_) ? vb[ibase + (size_t)srow * D_ + d] : 0;
    }
    __syncthreads();
    const int s = threadIdx.x & 63;
    const int d0 = threadIdx.x >> 6;
    const int scol = st * 64 + s;
    if (scol < S_) {
        #pragma unroll
        for (int p = 0; p < 16; ++p) {
            const int dd = d0 + p * 4;
            vt[obase + (size_t)dd * S_ + scol] = Ts[s * 65 + dd];
        }
    }
}

// ---------------------------------------------------------------------------
// qkv projection: ONE dense GEMM [M=8000,K=1024] x [K,N=3072].
// FINAL STRUCTURE: 2-barrier single-buffer m97 form, n-fast grid.
// Measured ladder on this kernel: 2-barrier 90.6 us / MfmaUtil 23 (best);
// 2ph-dbuf-noswz 97.9; 2ph+XCD-swz 104 (swizzle thrashes per-XCD L2,
// FETCH 75->85 MB). Do NOT revisit dbuf/swizzle here.
// ---------------------------------------------------------------------------
__global__ __launch_bounds__(256) void qkv_mfma_kernel(
    const unsigned short* __restrict__ xbf, const unsigned short* __restrict__ WT,
    const float* __restrict__ bq, const float* __restrict__ bk,
    const float* __restrict__ bv,
    unsigned short* __restrict__ qb, unsigned short* __restrict__ kb,
    unsigned short* __restrict__ vb)
{
    __shared__ unsigned short As[128 * 64];   // 16 KB, linear [row][64]
    __shared__ unsigned short Bs[128 * 64];   // 16 KB, linear [nrow][64]

    const int tid  = threadIdx.x;
    const int wave = tid >> 6, lane = tid & 63;
    const int m16  = lane & 15, quad = lane >> 4;
    const int wm   = wave >> 1, wn = wave & 1;
    const int n0   = blockIdx.x * 128;
    const int m0   = blockIdx.y * 128;

    f32x4 acc[4][4];   // [nf][mf]
    #pragma unroll
    for (int nf = 0; nf < 4; ++nf)
        #pragma unroll
        for (int mf = 0; mf < 4; ++mf)
            acc[nf][mf] = (f32x4){0.f, 0.f, 0.f, 0.f};

    const int lrow = lane >> 3;          // 0..7
    const int lcol = (lane & 7) << 3;    // 0,8,..,56

    int a_srow[4];
    #pragma unroll
    for (int j = 0; j < 4; ++j) {
        int r = m0 + (wave * 4 + j) * 8 + lrow;
        a_srow[j] = (r < M_) ? r : (M_ - 1);
    }

    for (int kk = 0; kk < E_; kk += 64) {
        __syncthreads();
        #pragma unroll
        for (int j = 0; j < 4; ++j) {
            const int i = wave * 4 + j;
            gld16(xbf + (size_t)a_srow[j] * E_ + kk + lcol, &As[i * 512]);
            gld16(WT + (size_t)(n0 + i * 8 + lrow) * E_ + kk + lcol, &Bs[i * 512]);
        }
        __syncthreads();

        #pragma unroll
        for (int kh = 0; kh < 2; ++kh) {
            const int ko = kh * 32 + quad * 8;
            bf16x8 af[4];
            #pragma unroll
            for (int mf = 0; mf < 4; ++mf)
                af[mf] = *(const bf16x8*)&As[(wm * 64 + mf * 16 + m16) * 64 + ko];
            #pragma unroll
            for (int nf = 0; nf < 4; ++nf) {
                const bf16x8 bfr = *(const bf16x8*)&Bs[(wn * 64 + nf * 16 + m16) * 64 + ko];
                #pragma unroll
                for (int mf = 0; mf < 4; ++mf)
                    acc[nf][mf] = __builtin_amdgcn_mfma_f32_16x16x32_bf16(
                        af[mf], bfr, acc[nf][mf], 0, 0, 0);
            }
        }
    }

    const int z = n0 >> 10;
    const int h = ((n0 >> 6) + wn) & 15;
    unsigned short* const ob = (z == 0) ? qb : (z == 1) ? kb : vb;
    const float* const bz    = (z == 0) ? bq : (z == 1) ? bk : bv;

    float biasv[4];
    #pragma unroll
    for (int nf = 0; nf < 4; ++nf)
        biasv[nf] = bz[h * D_ + nf * 16 + m16];

    #pragma unroll
    for (int mf = 0; mf < 4; ++mf)
        #pragma unroll
        for (int r = 0; r < 4; ++r) {
            const int row = m0 + wm * 64 + mf * 16 + quad * 4 + r;
            if (row < M_) {
                const int b = row / S_, s = row % S_;
                const size_t obase = (((size_t)b * H_ + h) * S_ + s) * D_ + m16;
                #pragma unroll
                for (int nf = 0; nf < 4; ++nf)
                    ob[obase + nf * 16] = f2bf(acc[nf][mf][r] + biasv[nf]);
            }
        }
}

// ---------------------------------------------------------------------------
// Flash attention. R15: QBLK 64 -> 128 via 8 waves (512 threads); per-wave
// loop body identical to the proven KVBLK=64 form (16 q-rows, 64-key tiles,
// setprio around MFMA clusters). Per (b,h): barrier-pairs 136 -> 72 (-47%),
// K/V staging -47%, MFMA +6% (one extra part-masked diagonal tile/q-block).
// LDS: Q-staging UNIONED with Ps (both exactly 9216 shorts; Q is consumed
// into regs before the first Ps write, two barriers in between) -> 36 KB
// -> 4 blocks/CU x 8 waves = 32 waves/CU (was 20). Masking applies to the
// last TWO tiles (tt >= nt-2); keys >= S=1000 only appear in masked tiles
// and the V-col guard at 8-granularity is exact (1000 % 8 == 0).
// NOTE: KVBLK=128 (R12) regressed — that scaled per-wave state; this scales
// wave count. Do not confuse the two.
// ---------------------------------------------------------------------------
__global__ __launch_bounds__(512) void attn_flash_kernel(
    const unsigned short* __restrict__ q, const unsigned short* __restrict__ k,
    const unsigned short* __restrict__ vt, unsigned short* __restrict__ ybf)
{
    constexpr int P_ = 72;
    __shared__ unsigned short QP[128 * P_];  // Q staging, then Ps[8][16*P_]
    __shared__ unsigned short Ks[64 * P_];
    __shared__ unsigned short Vt[64 * P_];   // [d][t]

    const int tid  = threadIdx.x;
    const int wave = tid >> 6, lane = tid & 63;
    const int m16  = lane & 15, quad = lane >> 4;
    const int jq = (int)gridDim.x - 1 - (int)blockIdx.x;   // long blocks first
    const int h = blockIdx.y, b = blockIdx.z;
    const size_t bh  = ((size_t)b * H_ + h) * S_;
    const size_t vtb = ((size_t)b * H_ + h) * (size_t)D_ * S_;
    const float sl2e = 0.031622776601683794f * 1.4426950408889634f;

    const int c8 = (tid & 7) * 8;
    const int r0 = tid >> 3;   // 0..63

    // stage Q: 128 rows, scaled, into QP
    #pragma unroll
    for (int rr = 0; rr < 128; rr += 64) {
        const int r = r0 + rr;
        const int srow = jq * 128 + r;
        u16x8 val = {0, 0, 0, 0, 0, 0, 0, 0};
        if (srow < S_) val = *(const u16x8*)(q + (bh + srow) * D_ + c8);
        u16x8 o;
        #pragma unroll
        for (int jj = 0; jj < 8; ++jj) o[jj] = f2bf_fast(bfr2f(val[jj]) * sl2e);
        *(u16x8*)&QP[r * P_ + c8] = o;
    }
    __syncthreads();

    // Q fragments to registers (QP is re-used as Ps after this; first Ps
    // write is after the 2nd barrier of iteration 0 -> strictly ordered).
    const bf16x8 qa0 = *(const bf16x8*)&QP[(wave * 16 + m16) * P_ + quad * 8];
    const bf16x8 qa1 = *(const bf16x8*)&QP[(wave * 16 + m16) * P_ + 32 + quad * 8];

    f32x4 O[4] = {{0,0,0,0},{0,0,0,0},{0,0,0,0},{0,0,0,0}};
    float l_i[4] = {0.f, 0.f, 0.f, 0.f};

    const int qrow_base = jq * 128 + wave * 16 + quad * 4;
    const int nt = 2 * jq + 2;   // 64-key tiles for this q-block

    // register prefetch of tile 0 (keys 0..63, always valid)
    u16x8 kreg = *(const u16x8*)(k + (bh + r0) * D_ + c8);
    u16x8 vreg = *(const u16x8*)(vt + vtb + (size_t)r0 * S_ + c8);

    for (int tt = 0; tt < nt; ++tt) {
        const int t0 = tt * 64;
        __syncthreads();
        *(u16x8*)&Ks[r0 * P_ + c8] = kreg;
        *(u16x8*)&Vt[r0 * P_ + c8] = vreg;
        __syncthreads();

        if (tt + 1 < nt) {
            const int nt0 = t0 + 64;
            const int srow = nt0 + r0;
            u16x8 kv = {0,0,0,0,0,0,0,0}, vv = {0,0,0,0,0,0,0,0};
            if (srow < S_) kv = *(const u16x8*)(k + (bh + srow) * D_ + c8);
            if (nt0 + c8 < S_)
                vv = *(const u16x8*)(vt + vtb + (size_t)r0 * S_ + nt0 + c8);
            kreg = kv; vreg = vv;
        }

        f32x4 sc[4];
        __builtin_amdgcn_s_setprio(1);
        #pragma unroll
        for (int ts = 0; ts < 4; ++ts) {
            const bf16x8 kb0 = *(const bf16x8*)&Ks[(ts * 16 + m16) * P_ + quad * 8];
            const bf16x8 kb1 = *(const bf16x8*)&Ks[(ts * 16 + m16) * P_ + 32 + quad * 8];
            f32x4 a = {0.f, 0.f, 0.f, 0.f};
            a = __builtin_amdgcn_mfma_f32_16x16x32_bf16(qa0, kb0, a, 0, 0, 0);
            a = __builtin_amdgcn_mfma_f32_16x16x32_bf16(qa1, kb1, a, 0, 0, 0);
            sc[ts] = a;
        }
        __builtin_amdgcn_s_setprio(0);

        unsigned short* const pw = &QP[wave * (16 * P_)];
        if (tt >= nt - 2) {
            #pragma unroll
            for (int ts = 0; ts < 4; ++ts) {
                const int t = t0 + ts * 16 + m16;
                #pragma unroll
                for (int r = 0; r < 4; ++r) {
                    float p = __builtin_amdgcn_exp2f(sc[ts][r]);
                    p = (t <= qrow_base + r) ? p : 0.f;
                    pw[(quad * 4 + r) * P_ + ts * 16 + m16] = f2bf_fast(p);
                    l_i[r] += p;
                }
            }
        } else {
            #pragma unroll
            for (int ts = 0; ts < 4; ++ts)
                #pragma unroll
                for (int r = 0; r < 4; ++r) {
                    const float p = __builtin_amdgcn_exp2f(sc[ts][r]);
                    pw[(quad * 4 + r) * P_ + ts * 16 + m16] = f2bf_fast(p);
                    l_i[r] += p;
                }
        }

        const bf16x8 pa0 = *(const bf16x8*)&pw[m16 * P_ + quad * 8];
        const bf16x8 pa1 = *(const bf16x8*)&pw[m16 * P_ + 32 + quad * 8];
        __builtin_amdgcn_s_setprio(1);
        #pragma unroll
        for (int db = 0; db < 4; ++db) {
            const bf16x8 vb0 = *(const bf16x8*)&Vt[(db * 16 + m16) * P_ + quad * 8];
            const bf16x8 vb1 = *(const bf16x8*)&Vt[(db * 16 + m16) * P_ + 32 + quad * 8];
            O[db] = __builtin_amdgcn_mfma_f32_16x16x32_bf16(pa0, vb0, O[db], 0, 0, 0);
            O[db] = __builtin_amdgcn_mfma_f32_16x16x32_bf16(pa1, vb1, O[db], 0, 0, 0);
        }
        __builtin_amdgcn_s_setprio(0);
    }

    #pragma unroll
    for (int off = 1; off < 16; off <<= 1)
        #pragma unroll
        for (int r = 0; r < 4; ++r)
            l_i[r] += __shfl_xor(l_i[r], off, 64);

    #pragma unroll
    for (int r = 0; r < 4; ++r) {
        const int qrow = qrow_base + r;
        if (qrow < S_) {
            const float invl = 1.0f / l_i[r];
            #pragma unroll
            for (int db = 0; db < 4; ++db)
                ybf[((size_t)b * S_ + qrow) * E_ + h * D_ + db * 16 + m16] =
                    f2bf(O[db][r] * invl);
        }
    }
}

// ---------------------------------------------------------------------------
// proj + exact GELU. m97 gload_lds 2-barrier single-buffer (R14-proven).
// grid (63 m-fast, 8 n): 63 consecutive blocks share one 256 KB B-panel.
// ---------------------------------------------------------------------------
__global__ __launch_bounds__(256) void proj_mfma_kernel(
    const unsigned short* __restrict__ ybf, const unsigned short* __restrict__ wpT,
    const float* __restrict__ bp, float* __restrict__ out)
{
    __shared__ unsigned short As[128 * 64];   // 16 KB, linear
    __shared__ unsigned short Bs[128 * 64];   // 16 KB, linear

    const int tid = threadIdx.x;
    const int wave = tid >> 6, lane = tid & 63;
    const int m16 = lane & 15, quad = lane >> 4;
    const int wm = wave >> 1, wn = wave & 1;
    const int m0 = blockIdx.x * 128;
    const int n0 = blockIdx.y * 128;

    f32x4 acc[4][4];
    #pragma unroll
    for (int nf = 0; nf < 4; ++nf)
        #pragma unroll
        for (int mf = 0; mf < 4; ++mf)
            acc[nf][mf] = (f32x4){0.f, 0.f, 0.f, 0.f};

    const int lrow = lane >> 3;          // 0..7
    const int lcol = (lane & 7) << 3;    // 0,8,..,56

    int a_srow[4];
    #pragma unroll
    for (int j = 0; j < 4; ++j) {
        int r = m0 + (wave * 4 + j) * 8 + lrow;
        a_srow[j] = (r < M_) ? r : (M_ - 1);
    }

    for (int kk = 0; kk < E_; kk += 64) {
        __syncthreads();
        #pragma unroll
        for (int j = 0; j < 4; ++j) {
            const int i = wave * 4 + j;
            gld16(ybf + (size_t)a_srow[j] * E_ + kk + lcol, &As[i * 512]);
            gld16(wpT + (size_t)(n0 + i * 8 + lrow) * E_ + kk + lcol, &Bs[i * 512]);
        }
        __syncthreads();

        #pragma unroll
        for (int kh = 0; kh < 2; ++kh) {
            const int ko = kh * 32 + quad * 8;
            bf16x8 af[4];
            #pragma unroll
            for (int mf = 0; mf < 4; ++mf)
                af[mf] = *(const bf16x8*)&As[(wm * 64 + mf * 16 + m16) * 64 + ko];
            #pragma unroll
            for (int nf = 0; nf < 4; ++nf) {
                const bf16x8 bfr = *(const bf16x8*)&Bs[(wn * 64 + nf * 16 + m16) * 64 + ko];
                #pragma unroll
                for (int mf = 0; mf < 4; ++mf)
                    acc[nf][mf] = __builtin_amdgcn_mfma_f32_16x16x32_bf16(
                        af[mf], bfr, acc[nf][mf], 0, 0, 0);
            }
        }
    }

    float biasv[4];
    #pragma unroll
    for (int nf = 0; nf < 4; ++nf)
        biasv[nf] = bp[n0 + wn * 64 + nf * 16 + m16];

    #pragma unroll
    for (int mf = 0; mf < 4; ++mf)
        #pragma unroll
        for (int r = 0; r < 4; ++r) {
            const int row = m0 + wm * 64 + mf * 16 + quad * 4 + r;
            if (row < M_) {
                #pragma unroll
                for (int nf = 0; nf < 4; ++nf) {
                    const int col = n0 + wn * 64 + nf * 16 + m16;
                    const float t = acc[nf][mf][r] + biasv[nf];
                    const float g = 0.5f * t * (1.0f + erff(t * 0.70710678118654752f));
                    out[(size_t)row * E_ + col] = g;
                }
            }
        }
}

// ---------------------------------------------------------------------------
extern "C" void kernel_launch(void* const* d_in, const int* in_sizes, int n_in,
                              void* d_out, int out_size, void* d_ws, size_t ws_size,
                              hipStream_t stream)
{
    const float* x  = (const float*)d_in[0];
    const float* wq = (const float*)d_in[1];
    const float* bq = (const float*)d_in[2];
    const float* wk = (const float*)d_in[3];
    const float* bk = (const float*)d_in[4];
    const float* wv = (const float*)d_in[5];
    const float* bv = (const float*)d_in[6];
    const float* wp = (const float*)d_in[7];
    const float* bp = (const float*)d_in[8];
    float* out = (float*)d_out;

    const size_t nME = (size_t)M_ * E_;          // 8,192,000
    unsigned short* xbf = (unsigned short*)d_ws;
    unsigned short* WT  = xbf + nME;             // 3,145,728
    unsigned short* wpT = WT + 3145728;          // 1,048,576
    unsigned short* qb  = wpT + 1048576;
    unsigned short* kb  = qb + nME;
    unsigned short* vb  = kb + nME;
    unsigned short* ybf = vb + nME;
    unsigned short* vtr = ybf + nME;             // v transposed [bh][d][S]

    cast_x_kernel<<<dim3((unsigned)(nME / 1024)), 256, 0, stream>>>(x, xbf);
    transpose_wqkv_kernel<<<dim3(16, 48), 256, 0, stream>>>(wq, wk, wv, WT);
    transpose_wp_kernel<<<dim3(16, 16), 256, 0, stream>>>(wp, wpT);

    // Single-GEMM qkv: grid (N-tiles=24 fastest, M-tiles=63).
    qkv_mfma_kernel<<<dim3(3072 / 128, (M_ + 127) / 128), 256, 0, stream>>>(
        xbf, WT, bq, bk, bv, qb, kb, vb);
    transpose_v_kernel<<<dim3(16, B_ * H_), 256, 0, stream>>>(vb, vtr);
    attn_flash_kernel<<<dim3((S_ + 127) / 128, H_, B_), 512, 0, stream>>>(
        qb, kb, vtr, ybf);
    proj_mfma_kernel<<<dim3((M_ + 127) / 128, E_ / 128), 256, 0, stream>>>(
        ybf, wpT, bp, out);
}